// Round 1
// baseline (407.799 us; speedup 1.0000x reference)
//
#include <hip/hip_runtime.h>

#define NB 128
#define LL 512
#define DD 768
#define JJ 32
#define SS 33
#define DM 200

typedef __attribute__((ext_vector_type(8))) short bf8_t;   // 8 bf16 (4 VGPRs)
typedef __attribute__((ext_vector_type(4))) float f4_t;    // MFMA C/D

static __device__ __forceinline__ unsigned short f2bf(float f) {
  unsigned u = __float_as_uint(f);
  return (unsigned short)((u + 0x7FFFu + ((u >> 16) & 1u)) >> 16);  // RNE
}

template<int KS>
static __device__ __forceinline__ f4_t mfma_tile(
    const unsigned short* pa, const unsigned short* pw)
{
  f4_t acc = {0.f, 0.f, 0.f, 0.f};
  bf8_t a = *(const bf8_t*)pa;
  bf8_t w = *(const bf8_t*)pw;
#pragma unroll
  for (int s = 1; s < KS; ++s) {
    bf8_t a2 = *(const bf8_t*)(pa + 32 * s);
    bf8_t w2 = *(const bf8_t*)(pw + 32 * s);
    acc = __builtin_amdgcn_mfma_f32_16x16x32_bf16(a, w, acc, 0, 0, 0);
    a = a2; w = w2;
  }
  acc = __builtin_amdgcn_mfma_f32_16x16x32_bf16(a, w, acc, 0, 0, 0);
  return acc;
}

template<int KS>
static __device__ __forceinline__ f4_t mfma_tile_lds(
    const unsigned short* pa, const unsigned short* pw)
{
  f4_t acc = {0.f, 0.f, 0.f, 0.f};
#pragma unroll
  for (int s = 0; s < KS; ++s) {
    bf8_t a = *(const bf8_t*)(pa + 32 * s);
    bf8_t w = *(const bf8_t*)(pw + 32 * s);
    acc = __builtin_amdgcn_mfma_f32_16x16x32_bf16(a, w, acc, 0, 0, 0);
  }
  return acc;
}

#define CVT_FC1 159744   // 208*768
#define CVT_AIN 136192   // 608*224
#define CVT_OTH 46592    // 208*224

// ---------------------------------------------------------------------------
// PC kernel: blocks [0, 4224) = single-pass fused pool (LDS row staging +
// chunked online softmax); blocks [4224, 4224+851) = weight bf16 convert.
// ---------------------------------------------------------------------------
__global__ __launch_bounds__(512) void pc_kernel(
    const float* __restrict__ hidden, const int* __restrict__ clause,
    const float* __restrict__ fc5w, unsigned short* __restrict__ pooled_bf,
    const float* __restrict__ fc1_w, const float* __restrict__ ain_w,
    const float* __restrict__ aout_w, const float* __restrict__ lin1_w,
    const float* __restrict__ lin2_w,
    unsigned short* __restrict__ fc1_wb, unsigned short* __restrict__ ain_wb,
    unsigned short* __restrict__ aout_wb, unsigned short* __restrict__ lin1_wb,
    unsigned short* __restrict__ lin2_wb)
{
  const int tid = threadIdx.x;
  if (blockIdx.x >= NB * SS) {
    int t = (blockIdx.x - NB * SS) * 512 + tid;
    if (t < CVT_FC1) { int n = t / 768, k = t - n * 768;
      fc1_wb[t] = f2bf((n < DM) ? fc1_w[n * 768 + k] : 0.f); return; }
    t -= CVT_FC1;
    if (t < CVT_AIN) { int n = t / 224, k = t - n * 224;
      ain_wb[t] = f2bf((n < 600 && k < DM) ? ain_w[n * DM + k] : 0.f); return; }
    t -= CVT_AIN;
    if (t < CVT_OTH) { int n = t / 224, k = t - n * 224;
      aout_wb[t] = f2bf((n < DM && k < DM) ? aout_w[n * DM + k] : 0.f); return; }
    t -= CVT_OTH;
    if (t < CVT_OTH) { int n = t / 224, k = t - n * 224;
      lin1_wb[t] = f2bf((n < DM && k < DM) ? lin1_w[n * DM + k] : 0.f); return; }
    t -= CVT_OTH;
    if (t < CVT_OTH) { int n = t / 224, k = t - n * 224;
      lin2_wb[t] = f2bf((n < DM && k < DM) ? lin2_w[n * DM + k] : 0.f); }
    return;
  }

  // -------- pool: block = (b, s); hidden read from HBM exactly once --------
  __shared__ __align__(16) float rows[16][768];   // 48 KB -> 2 blocks/CU
  __shared__ float sc[16], wts[16];
  __shared__ float mprev, denom, rfac;

  int blk = blockIdx.x;
  int b = blk / SS, s = blk - b * SS;
  int t0 = (s == 0) ? 0 : clause[b * JJ + s - 1];
  int t1 = (s == JJ) ? LL : clause[b * JJ + s];
  int nt = t1 - t0;
  if (nt > 64) nt = 64;
  if (nt < 1) nt = 1;

  int wave = tid >> 6, lane = tid & 63;
  if (tid == 0) { mprev = -__builtin_inff(); denom = 0.f; }

  float2 acc = make_float2(0.f, 0.f);
  const float4* w4 = (const float4*)fc5w;
  int nchunk = (nt + 15) >> 4;
  for (int c = 0; c < nchunk; ++c) {
    int c0 = t0 + (c << 4);
    int cn = nt - (c << 4); if (cn > 16) cn = 16;
    // A: load rows to LDS (f32) + score per row
    for (int tt = wave; tt < cn; tt += 8) {
      const float4* hp = (const float4*)(hidden + ((long long)b * LL + c0 + tt) * DD);
      float4 v0 = hp[lane], v1 = hp[lane + 64], v2 = hp[lane + 128];
      float4 wa = w4[lane], wb = w4[lane + 64], wc = w4[lane + 128];
      float d = v0.x*wa.x + v0.y*wa.y + v0.z*wa.z + v0.w*wa.w
              + v1.x*wb.x + v1.y*wb.y + v1.z*wb.z + v1.w*wb.w
              + v2.x*wc.x + v2.y*wc.y + v2.z*wc.z + v2.w*wc.w;
#pragma unroll
      for (int off = 32; off; off >>= 1) d += __shfl_xor(d, off);
      float4* rp = (float4*)rows[tt];
      rp[lane] = v0; rp[lane + 64] = v1; rp[lane + 128] = v2;
      if (lane == 0) sc[tt] = d;
    }
    __syncthreads();
    // B: online softmax update (wave 0)
    if (wave == 0) {
      float v = (lane < cn) ? sc[lane] : -__builtin_inff();
      float mc = v;
#pragma unroll
      for (int off = 32; off; off >>= 1) mc = fmaxf(mc, __shfl_xor(mc, off));
      float mold = mprev;
      float mnew = fmaxf(mold, mc);
      float rr = __expf(mold - mnew);
      float e = (lane < cn) ? __expf(v - mnew) : 0.f;
      float sm = e;
#pragma unroll
      for (int off = 32; off; off >>= 1) sm += __shfl_xor(sm, off);
      if (lane < 16) wts[lane] = e;
      if (lane == 0) { denom = denom * rr + sm; mprev = mnew; rfac = rr; }
    }
    __syncthreads();
    // C: weighted accumulate from LDS
    if (tid < 384) {
      float rr = rfac;
      acc.x *= rr; acc.y *= rr;
#pragma unroll 4
      for (int tt = 0; tt < cn; ++tt) {
        float w = wts[tt];
        float2 h = ((const float2*)rows[tt])[tid];
        acc.x = fmaf(w, h.x, acc.x);
        acc.y = fmaf(w, h.y, acc.y);
      }
    }
    __syncthreads();
  }
  if (tid < 384) {
    float inv = 1.f / denom;
    ushort2 o;
    o.x = f2bf(acc.x * inv);
    o.y = f2bf(acc.y * inv);
    *(ushort2*)(pooled_bf + (size_t)blk * DD + tid * 2) = o;
  }
}

// ---------------------------------------------------------------------------
// k_tx: one block per batch. fc1 -> qkv -> attn -> aout+res -> LN1 -> FFN ->
// LN2 -> classifier, all intermediates in LDS (155 KB, liveness-overlaid).
// ---------------------------------------------------------------------------
__global__ __launch_bounds__(512) void k_tx(
    const unsigned short* __restrict__ pooled,
    const unsigned short* __restrict__ fc1_wb, const float* __restrict__ fc1_b,
    const unsigned short* __restrict__ ain_wb, const float* __restrict__ ain_b,
    const unsigned short* __restrict__ aout_wb, const float* __restrict__ aout_b,
    const float* __restrict__ ln1_g, const float* __restrict__ ln1_b,
    const unsigned short* __restrict__ lin1_wb, const float* __restrict__ lin1_b,
    const unsigned short* __restrict__ lin2_wb, const float* __restrict__ lin2_b,
    const float* __restrict__ ln2_g, const float* __restrict__ ln2_b,
    const float* __restrict__ fcw, const float* __restrict__ fcb,
    float* __restrict__ out)
{
  const int b = blockIdx.x;
  const int tid = threadIdx.x, wv = tid >> 6, lane = tid & 63;
  const int col = lane & 15, quad = lane >> 4, koff = quad * 8;

  __shared__ __align__(16) char smem[159168];
  float*          xf  = (float*)(smem);                   // [48][209] f32 x, then y, then y2
  unsigned short* xb  = (unsigned short*)(smem + 40128);  // [48][232] bf16 (dead after Ph2)
  float*          scb = (float*)(smem + 40128);           // [48][56] f32 scores (over xb)
  unsigned short* qb  = (unsigned short*)(smem + 62400);  // [48][232] (dead after Ph3)
  unsigned short* kb  = (unsigned short*)(smem + 84672);  // [48][232] (dead after Ph3)
  unsigned short* Pb  = (unsigned short*)(smem + 62400);  // [48][72]  (over qb)
  unsigned short* yb  = (unsigned short*)(smem + 69312);  // [48][232] (over qb/kb tail)
  unsigned short* vt  = (unsigned short*)(smem + 106944); // [208][72] V^T
  unsigned short* fb  = (unsigned short*)(smem + 136896); // [48][232] att then f1

  // zero pad columns / vt (everything MFMA might read before it's written)
  for (int u = tid; u < 768; u += 512) { int r = u >> 4, c2 = u & 15;
    ((unsigned*)(xb + r * 232 + 200))[c2] = 0u; }
  for (int u = tid; u < 768; u += 512) { int r = u >> 4, c2 = u & 15;
    ((unsigned*)(qb + r * 232 + 200))[c2] = 0u; }
  for (int u = tid; u < 768; u += 512) { int r = u >> 4, c2 = u & 15;
    ((unsigned*)(kb + r * 232 + 200))[c2] = 0u; }
  for (int u = tid; u < 768; u += 512) { int r = u >> 4, c2 = u & 15;
    ((unsigned*)(fb + r * 232 + 200))[c2] = 0u; }
  for (int u = tid; u < 7488; u += 512) ((unsigned*)vt)[u] = 0u;
  __syncthreads();

  // ---- Ph1: x = pooled @ fc1^T + b  (39 jobs) ----
  const unsigned short* Ab = pooled + (size_t)b * SS * DD;
  for (int jj = wv; jj < 39; jj += 8) {
    int mt = jj / 13, t = jj - mt * 13;
    int m0 = mt * 16, n0 = t * 16, gn = n0 + col;
    int ar = m0 + col; if (ar > 32) ar = 32;
    f4_t acc = mfma_tile<24>(Ab + (size_t)ar * DD + koff,
                             fc1_wb + (size_t)gn * DD + koff);
    if (gn < DM) {
      float bv = fc1_b[gn];
#pragma unroll
      for (int r = 0; r < 4; ++r) {
        int row = m0 + quad * 4 + r;
        float v = acc[r] + bv;
        xf[row * 209 + gn] = v;
        xb[row * 232 + gn] = f2bf(v);
      }
    }
  }
  __syncthreads();

  // ---- Ph2: qkv = x @ ain^T + b -> qb/kb/vt  (114 jobs) ----
  for (int jj = wv; jj < 114; jj += 8) {
    int mt = jj / 38, t = jj - mt * 38;
    int m0 = mt * 16, n0 = t * 16, gn = n0 + col;
    f4_t acc = mfma_tile_lds<7>(xb + (m0 + col) * 232 + koff,
                                ain_wb + (size_t)gn * 224 + koff);
    if (gn < 600) {
      float bv = ain_b[gn];
#pragma unroll
      for (int r = 0; r < 4; ++r) {
        int gm = m0 + quad * 4 + r;
        unsigned short bfv = f2bf(acc[r] + bv);
        if (gn < DM)       qb[gm * 232 + gn] = bfv;
        else if (gn < 400) kb[gm * 232 + (gn - DM)] = bfv;
        else if (gm < SS)  vt[(gn - 400) * 72 + gm] = bfv;    // V^T
      }
    }
  }
  __syncthreads();

  // ---- Ph3: scores = q @ k^T * scale  (9 jobs) -> scb (over xb) ----
  for (int jj = wv; jj < 9; jj += 8) {
    int mt = jj / 3, t = jj - mt * 3;
    int m0 = mt * 16, n0 = t * 16;
    f4_t acc = mfma_tile_lds<7>(qb + (m0 + col) * 232 + koff,
                                kb + (n0 + col) * 232 + koff);
#pragma unroll
    for (int r = 0; r < 4; ++r)
      scb[(m0 + quad * 4 + r) * 56 + n0 + col] = acc[r] * 0.07071067811865475f;
  }
  __syncthreads();

  // ---- Ph4: softmax rows -> Pb bf16 (over qb; qb/kb dead) ----
  for (int r = wv; r < 48; r += 8) {
    bool live = r < SS;
    float v = (lane < SS && live) ? scb[r * 56 + lane] : -__builtin_inff();
    float mx = v;
#pragma unroll
    for (int off = 32; off; off >>= 1) mx = fmaxf(mx, __shfl_xor(mx, off));
    float e = (lane < SS && live) ? __expf(v - mx) : 0.f;
    float sm = e;
#pragma unroll
    for (int off = 32; off; off >>= 1) sm += __shfl_xor(sm, off);
    Pb[r * 72 + lane] = (lane < SS && live) ? f2bf(e / sm) : (unsigned short)0;
  }
  __syncthreads();

  // ---- Ph5: att = P @ V  (39 jobs, K=64) -> fb ----
  for (int jj = wv; jj < 39; jj += 8) {
    int mt = jj / 13, t = jj - mt * 13;
    int m0 = mt * 16, n0 = t * 16, gn = n0 + col;
    f4_t acc = mfma_tile_lds<2>(Pb + (m0 + col) * 72 + koff,
                                vt + (size_t)gn * 72 + koff);
    if (gn < DM) {
#pragma unroll
      for (int r = 0; r < 4; ++r)
        fb[(m0 + quad * 4 + r) * 232 + gn] = f2bf(acc[r]);
    }
  }
  __syncthreads();

  // ---- Ph6: y_pre = x + att @ aout^T + b  -> xf in place ----
  for (int jj = wv; jj < 39; jj += 8) {
    int mt = jj / 13, t = jj - mt * 13;
    int m0 = mt * 16, n0 = t * 16, gn = n0 + col;
    f4_t acc = mfma_tile_lds<7>(fb + (m0 + col) * 232 + koff,
                                aout_wb + (size_t)gn * 224 + koff);
    if (gn < DM) {
      float bv = aout_b[gn];
#pragma unroll
      for (int r = 0; r < 4; ++r) {
        int row = m0 + quad * 4 + r;
        xf[row * 209 + gn] += acc[r] + bv;
      }
    }
  }
  __syncthreads();

  // ---- Ph7: LN1 -> xf in place + yb bf16 (+ zero yb pad cols) ----
  for (int r = wv; r < 48; r += 8) {
    float* p = xf + r * 209;
    float vals[4]; float sm = 0.f;
#pragma unroll
    for (int i = 0; i < 4; ++i) { int k = lane + 64 * i; vals[i] = (k < DM) ? p[k] : 0.f; sm += vals[i]; }
#pragma unroll
    for (int off = 32; off; off >>= 1) sm += __shfl_xor(sm, off);
    float mean = sm * (1.f / DM);
    float vs = 0.f;
#pragma unroll
    for (int i = 0; i < 4; ++i) { int k = lane + 64 * i; if (k < DM) { float d2 = vals[i] - mean; vs += d2 * d2; } }
#pragma unroll
    for (int off = 32; off; off >>= 1) vs += __shfl_xor(vs, off);
    float rstd = rsqrtf(vs * (1.f / DM) + 1e-5f);
#pragma unroll
    for (int i = 0; i < 4; ++i) {
      int k = lane + 64 * i;
      if (k < DM) {
        float o = (vals[i] - mean) * rstd * ln1_g[k] + ln1_b[k];
        p[k] = o;
        yb[r * 232 + k] = f2bf(o);
      } else if (k < 232) {
        yb[r * 232 + k] = 0;
      }
    }
  }
  __syncthreads();

  // ---- Ph8: f1 = relu(y @ lin1^T + b) -> fb ----
  for (int jj = wv; jj < 39; jj += 8) {
    int mt = jj / 13, t = jj - mt * 13;
    int m0 = mt * 16, n0 = t * 16, gn = n0 + col;
    f4_t acc = mfma_tile_lds<7>(yb + (m0 + col) * 232 + koff,
                                lin1_wb + (size_t)gn * 224 + koff);
    if (gn < DM) {
      float bv = lin1_b[gn];
#pragma unroll
      for (int r = 0; r < 4; ++r)
        fb[(m0 + quad * 4 + r) * 232 + gn] = f2bf(fmaxf(acc[r] + bv, 0.f));
    }
  }
  __syncthreads();

  // ---- Ph9: y2_pre = y + f1 @ lin2^T + b -> xf in place ----
  for (int jj = wv; jj < 39; jj += 8) {
    int mt = jj / 13, t = jj - mt * 13;
    int m0 = mt * 16, n0 = t * 16, gn = n0 + col;
    f4_t acc = mfma_tile_lds<7>(fb + (m0 + col) * 232 + koff,
                                lin2_wb + (size_t)gn * 224 + koff);
    if (gn < DM) {
      float bv = lin2_b[gn];
#pragma unroll
      for (int r = 0; r < 4; ++r) {
        int row = m0 + quad * 4 + r;
        xf[row * 209 + gn] += acc[r] + bv;
      }
    }
  }
  __syncthreads();

  // ---- Ph10: LN2 -> xf in place ----
  for (int r = wv; r < 48; r += 8) {
    float* p = xf + r * 209;
    float vals[4]; float sm = 0.f;
#pragma unroll
    for (int i = 0; i < 4; ++i) { int k = lane + 64 * i; vals[i] = (k < DM) ? p[k] : 0.f; sm += vals[i]; }
#pragma unroll
    for (int off = 32; off; off >>= 1) sm += __shfl_xor(sm, off);
    float mean = sm * (1.f / DM);
    float vs = 0.f;
#pragma unroll
    for (int i = 0; i < 4; ++i) { int k = lane + 64 * i; if (k < DM) { float d2 = vals[i] - mean; vs += d2 * d2; } }
#pragma unroll
    for (int off = 32; off; off >>= 1) vs += __shfl_xor(vs, off);
    float rstd = rsqrtf(vs * (1.f / DM) + 1e-5f);
#pragma unroll
    for (int i = 0; i < 4; ++i) {
      int k = lane + 64 * i;
      if (k < DM) p[k] = (vals[i] - mean) * rstd * ln2_g[k] + ln2_b[k];
    }
  }
  __syncthreads();

  // ---- Ph11: classifier ----
  for (int j = wv; j < 32; j += 8) {
    const float* r0 = xf;
    const float* rj = xf + (1 + j) * 209;
    float a0 = 0.f, a1 = 0.f;
    for (int k = lane; k < DM; k += 64) {
      float u = r0[k], w = rj[k];
      a0 += u * fcw[k]       + w * fcw[200 + k];
      a1 += u * fcw[400 + k] + w * fcw[600 + k];
    }
#pragma unroll
    for (int off = 32; off; off >>= 1) {
      a0 += __shfl_xor(a0, off);
      a1 += __shfl_xor(a1, off);
    }
    if (lane == 0) {
      out[(b * 32 + j) * 2 + 0] = a0 + fcb[0];
      out[(b * 32 + j) * 2 + 1] = a1 + fcb[1];
    }
  }
}

// ---------------------------------------------------------------------------
extern "C" void kernel_launch(void* const* d_in, const int* in_sizes, int n_in,
                              void* d_out, int out_size, void* d_ws, size_t ws_size,
                              hipStream_t stream)
{
  (void)in_sizes; (void)n_in; (void)out_size; (void)ws_size;
  const float* hidden = (const float*)d_in[0];
  const int*   clause = (const int*)d_in[1];
  const float* fc5_w  = (const float*)d_in[2];
  const float* fc1_w  = (const float*)d_in[4];
  const float* fc1_b  = (const float*)d_in[5];
  const float* ain_w  = (const float*)d_in[6];
  const float* ain_b  = (const float*)d_in[7];
  const float* aout_w = (const float*)d_in[8];
  const float* aout_b = (const float*)d_in[9];
  const float* ln1_g  = (const float*)d_in[10];
  const float* ln1_b  = (const float*)d_in[11];
  const float* lin1_w = (const float*)d_in[12];
  const float* lin1_b = (const float*)d_in[13];
  const float* lin2_w = (const float*)d_in[14];
  const float* lin2_b = (const float*)d_in[15];
  const float* ln2_g  = (const float*)d_in[16];
  const float* ln2_b  = (const float*)d_in[17];
  const float* fc_w   = (const float*)d_in[18];
  const float* fc_b   = (const float*)d_in[19];
  float* out = (float*)d_out;

  char* w8 = (char*)d_ws;
  unsigned short* pooled_bf = (unsigned short*)(w8 + 0);        // 4224*768*2 = 6488064
  unsigned short* fc1_wb  = (unsigned short*)(w8 + 6488064);    // 319488
  unsigned short* ain_wb  = (unsigned short*)(w8 + 6807552);    // 272384
  unsigned short* aout_wb = (unsigned short*)(w8 + 7079936);    // 93184
  unsigned short* lin1_wb = (unsigned short*)(w8 + 7173120);    // 93184
  unsigned short* lin2_wb = (unsigned short*)(w8 + 7266304);    // 93184

  // 4224 pool blocks + 851 convert blocks
  pc_kernel<<<dim3(NB * SS + 851), 512, 0, stream>>>(
      hidden, clause, fc5_w, pooled_bf,
      fc1_w, ain_w, aout_w, lin1_w, lin2_w,
      fc1_wb, ain_wb, aout_wb, lin1_wb, lin2_wb);
  k_tx<<<dim3(NB), 512, 0, stream>>>(pooled_bf, fc1_wb, fc1_b,
      ain_wb, ain_b, aout_wb, aout_b, ln1_g, ln1_b,
      lin1_wb, lin1_b, lin2_wb, lin2_b, ln2_g, ln2_b, fc_w, fc_b, out);
}

// Round 2
// 374.654 us; speedup vs baseline: 1.0885x; 1.0885x over previous
//
#include <hip/hip_runtime.h>

#define NB 128
#define LL 512
#define DD 768
#define JJ 32
#define SS 33
#define DM 200

typedef __attribute__((ext_vector_type(8))) short bf8_t;   // 8 bf16 (4 VGPRs)
typedef __attribute__((ext_vector_type(4))) float f4_t;    // MFMA C/D

// per-batch scratch block (bytes)
#define SB_XF   0                 // x_f32 [48][208] f32
#define SB_QB   61440             // q_bf  [48][224]
#define SB_KB   82944             // k_bf  [48][224]
#define SB_VT   104448            // vt_bf [208][64]
#define SB_Y2   235520            // y2_f32[48][208] f32
#define SB_BLK  275456

static __device__ __forceinline__ unsigned short f2bf(float f) {
  unsigned u = __float_as_uint(f);
  return (unsigned short)((u + 0x7FFFu + ((u >> 16) & 1u)) >> 16);  // RNE
}

template<int KS>
static __device__ __forceinline__ f4_t mfma_tile(
    const unsigned short* pa, const unsigned short* pw)
{
  f4_t acc = {0.f, 0.f, 0.f, 0.f};
  bf8_t a = *(const bf8_t*)pa;
  bf8_t w = *(const bf8_t*)pw;
#pragma unroll
  for (int s = 1; s < KS; ++s) {
    bf8_t a2 = *(const bf8_t*)(pa + 32 * s);
    bf8_t w2 = *(const bf8_t*)(pw + 32 * s);
    acc = __builtin_amdgcn_mfma_f32_16x16x32_bf16(a, w, acc, 0, 0, 0);
    a = a2; w = w2;
  }
  acc = __builtin_amdgcn_mfma_f32_16x16x32_bf16(a, w, acc, 0, 0, 0);
  return acc;
}

template<int KS>
static __device__ __forceinline__ f4_t mfma_tile_lds(
    const unsigned short* pa, const unsigned short* pw)
{
  f4_t acc = {0.f, 0.f, 0.f, 0.f};
#pragma unroll
  for (int s = 0; s < KS; ++s) {
    bf8_t a = *(const bf8_t*)(pa + 32 * s);
    bf8_t w = *(const bf8_t*)(pw + 32 * s);
    acc = __builtin_amdgcn_mfma_f32_16x16x32_bf16(a, w, acc, 0, 0, 0);
  }
  return acc;
}

// ---------------------------------------------------------------------------
// PC kernel: blocks [0, 4224) = fused pool; blocks [4224, ...) = weight
// convert + scratch pad-zero.
// ---------------------------------------------------------------------------
__global__ __launch_bounds__(512) void pc_kernel(
    const float* __restrict__ hidden, const int* __restrict__ clause,
    const float* __restrict__ fc5w, unsigned short* __restrict__ pooled_bf,
    const float* __restrict__ fc1_w, const float* __restrict__ ain_w,
    const float* __restrict__ aout_w, const float* __restrict__ lin1_w,
    const float* __restrict__ lin2_w,
    unsigned short* __restrict__ fc1_wb, unsigned short* __restrict__ ain_wb,
    unsigned short* __restrict__ aout_wb, unsigned short* __restrict__ lin1_wb,
    unsigned short* __restrict__ lin2_wb, char* __restrict__ scratch)
{
  const int tid = threadIdx.x;
  if (blockIdx.x >= NB * SS) {
    int t = (blockIdx.x - NB * SS) * 512 + tid;
    if (t < 208 * 768) {
      int n = t / 768, k = t - n * 768;
      fc1_wb[t] = f2bf((n < 200) ? fc1_w[n * 768 + k] : 0.f);
      return;
    }
    t -= 208 * 768;
    if (t < 608 * 224) {
      int n = t / 224, k = t - n * 224;
      ain_wb[t] = f2bf((n < 600 && k < 200) ? ain_w[n * 200 + k] : 0.f);
      return;
    }
    t -= 608 * 224;
    if (t < 208 * 224) {
      int n = t / 224, k = t - n * 224;
      aout_wb[t] = f2bf((n < 200 && k < 200) ? aout_w[n * 200 + k] : 0.f);
      return;
    }
    t -= 208 * 224;
    if (t < 208 * 224) {
      int n = t / 224, k = t - n * 224;
      lin1_wb[t] = f2bf((n < 200 && k < 200) ? lin1_w[n * 200 + k] : 0.f);
      return;
    }
    t -= 208 * 224;
    if (t < 208 * 224) {
      int n = t / 224, k = t - n * 224;
      lin2_wb[t] = f2bf((n < 200 && k < 200) ? lin2_w[n * 200 + k] : 0.f);
      return;
    }
    t -= 208 * 224;
    if (t < NB * 1344) {          // pad-zero: QB/KB cols 192-223, VT cols 32-63
      int b = t / 1344, r = t - b * 1344;
      char* sb = scratch + (size_t)b * SB_BLK;
      const uint4 z = make_uint4(0, 0, 0, 0);
      if (r < 384) {
        int bi = r / 192, rr = r - bi * 192;
        int row = rr >> 2, c = rr & 3;
        int off = (bi == 0) ? SB_QB : SB_KB;
        *(uint4*)((unsigned short*)(sb + off) + row * 224 + 192 + c * 8) = z;
      } else {
        int rr = r - 384;
        int row = rr >> 2, c = rr & 3;
        *(uint4*)((unsigned short*)(sb + SB_VT) + row * 64 + 32 + c * 8) = z;
      }
    }
    return;
  }

  // -------- pool part: block = (b, s) --------
  int blk = blockIdx.x;
  int b = blk / SS;
  int s = blk - b * SS;
  int t0 = (s == 0) ? 0 : clause[b * JJ + s - 1];
  int t1 = (s == JJ) ? LL : clause[b * JJ + s];
  int nt = t1 - t0;
  if (nt > 64) nt = 64;
  if (nt < 1) nt = 1;

  __shared__ float wsm[64];
  int wave = tid >> 6, lane = tid & 63;

  const float4* w4 = (const float4*)fc5w;
  float4 wa = w4[lane], wwb = w4[lane + 64], wc = w4[lane + 128];
  for (int t = t0 + wave; t < t0 + nt; t += 8) {
    const float4* hp = (const float4*)(hidden + ((long long)b * LL + t) * DD);
    float4 h0 = hp[lane], h1 = hp[lane + 64], h2 = hp[lane + 128];
    float acc = h0.x*wa.x + h0.y*wa.y + h0.z*wa.z + h0.w*wa.w
              + h1.x*wwb.x + h1.y*wwb.y + h1.z*wwb.z + h1.w*wwb.w
              + h2.x*wc.x + h2.y*wc.y + h2.z*wc.z + h2.w*wc.w;
#pragma unroll
    for (int off = 32; off; off >>= 1) acc += __shfl_xor(acc, off);
    if (lane == 0) wsm[t - t0] = acc;
  }
  __syncthreads();

  if (wave == 0) {
    float v = (lane < nt) ? wsm[lane] : -__builtin_inff();
    float mx = v;
#pragma unroll
    for (int off = 32; off; off >>= 1) mx = fmaxf(mx, __shfl_xor(mx, off));
    float e = (lane < nt) ? __expf(v - mx) : 0.f;
    float sm = e;
#pragma unroll
    for (int off = 32; off; off >>= 1) sm += __shfl_xor(sm, off);
    if (lane < nt) wsm[lane] = e / sm;
  }
  __syncthreads();

  if (tid < 384) {
    const float2* base = (const float2*)(hidden + ((long long)b * LL + t0) * DD);
    float2 acc = make_float2(0.f, 0.f);
#pragma unroll 4
    for (int t = 0; t < nt; ++t) {
      float w = wsm[t];
      float2 h = base[t * 384 + tid];
      acc.x = fmaf(w, h.x, acc.x);
      acc.y = fmaf(w, h.y, acc.y);
    }
    ushort2 o;
    o.x = f2bf(acc.x); o.y = f2bf(acc.y);
    *(ushort2*)(pooled_bf + (long long)blk * DD + tid * 2) = o;
  }
}

// ---------------------------------------------------------------------------
// K1: per (b, mt), 512 thr: stage A-tile (16 pooled rows) in LDS, then
// x = pooled@fc1^T + b (13 tiles, x -> LDS+global), qkv = x@ain^T + b
// (38 tiles) routed to q/k/vt scratch.
// ---------------------------------------------------------------------------
__global__ __launch_bounds__(512, 4) void k_fc1qkv(
    const unsigned short* __restrict__ pooled,
    const unsigned short* __restrict__ fc1_wb, const float* __restrict__ fc1_b,
    const unsigned short* __restrict__ ain_wb, const float* __restrict__ ain_b,
    char* __restrict__ scratch)
{
  const int b = blockIdx.x / 3, mt = blockIdx.x % 3, m0 = mt * 16;
  const int tid = threadIdx.x, wv = tid >> 6, lane = tid & 63;
  const int col = lane & 15, quad = lane >> 4, koff = quad * 8;

  char* sb = scratch + (size_t)b * SB_BLK;
  float* x_f32 = (float*)(sb + SB_XF);
  unsigned short* q_bf  = (unsigned short*)(sb + SB_QB);
  unsigned short* k_bf  = (unsigned short*)(sb + SB_KB);
  unsigned short* vt_bf = (unsigned short*)(sb + SB_VT);

  __shared__ __align__(16) unsigned short sA[16][776];  // stride 776: row shift 4 banks
  __shared__ __align__(16) unsigned short xb[16][232];

  // stage A-tile: 16 rows x 768 bf16 (row src clamped to 32 for dead rows)
  {
    int r = tid >> 5, c = tid & 31;
    int src = m0 + r; if (src > 32) src = 32;
    const unsigned* gp = (const unsigned*)(pooled + (size_t)(b * SS + src) * DD);
    unsigned* lp = (unsigned*)&sA[r][0];
#pragma unroll
    for (int i = 0; i < 12; ++i) lp[c + 32 * i] = gp[c + 32 * i];
  }
  for (int u = tid; u < 16 * 16; u += 512) {
    int row = u >> 4, c = u & 15;
    ((unsigned*)&xb[row][200])[c] = 0u;
  }
  __syncthreads();

  for (int t = wv; t < 13; t += 8) {
    int n0 = t * 16;
    f4_t acc = mfma_tile_lds<24>(&sA[0][0] + col * 776 + koff,
                                 fc1_wb + (size_t)(n0 + col) * DD + koff);
    int gn = n0 + col;
    if (gn < DM) {
      float bv = fc1_b[gn];
#pragma unroll
      for (int r = 0; r < 4; ++r) {
        int row = quad * 4 + r;
        float v = acc[r] + bv;
        x_f32[(m0 + row) * 208 + gn] = v;
        xb[row][gn] = f2bf(v);
      }
    }
  }
  __syncthreads();

  for (int t = wv; t < 38; t += 8) {
    int n0 = t * 16;
    f4_t acc = mfma_tile_lds<7>(&xb[0][0] + col * 232 + koff,
                                ain_wb + (size_t)(n0 + col) * 224 + koff);
    int gn = n0 + col;
    if (gn < 600) {
      float bv = ain_b[gn];
#pragma unroll
      for (int r = 0; r < 4; ++r) {
        int gm = m0 + quad * 4 + r;
        unsigned short bfv = f2bf(acc[r] + bv);
        if (gn < 200)      q_bf[gm * 224 + gn] = bfv;
        else if (gn < 400) k_bf[gm * 224 + (gn - 200)] = bfv;
        else if (gm < SS)  vt_bf[(gn - 400) * 64 + gm] = bfv;   // V^T
      }
    }
  }
}

// ---------------------------------------------------------------------------
// K2: per (b, mt), 512 thr: 16 own Q-rows through attention + aout + LN1 +
// FFN + LN2, all intermediates in LDS. y2 -> global scratch.
// ---------------------------------------------------------------------------
__global__ __launch_bounds__(512, 4) void k_postattn(
    const unsigned short* __restrict__ aout_wb, const float* __restrict__ aout_b,
    const float* __restrict__ ln1_g, const float* __restrict__ ln1_b,
    const unsigned short* __restrict__ lin1_wb, const float* __restrict__ lin1_b,
    const unsigned short* __restrict__ lin2_wb, const float* __restrict__ lin2_b,
    const float* __restrict__ ln2_g, const float* __restrict__ ln2_b,
    char* __restrict__ scratch)
{
  const int b = blockIdx.x / 3, mt = blockIdx.x % 3, m0 = mt * 16;
  const int tid = threadIdx.x, wv = tid >> 6, lane = tid & 63;
  const int col = lane & 15, quad = lane >> 4, koff = quad * 8;

  char* sb = scratch + (size_t)b * SB_BLK;
  const unsigned short* q_bf  = (const unsigned short*)(sb + SB_QB);
  const unsigned short* k_bf  = (const unsigned short*)(sb + SB_KB);
  const unsigned short* vt_bf = (const unsigned short*)(sb + SB_VT);
  const float* x_f32 = (const float*)(sb + SB_XF);
  float* y2g = (float*)(sb + SB_Y2);

  __shared__ float tc[16][211];                         // scores then C-tile
  __shared__ __align__(16) unsigned short Pb[16][72];   // softmax(P) bf16
  __shared__ __align__(16) unsigned short yb[16][232];  // LN1 out bf16
  __shared__ __align__(16) unsigned short fb[16][232];  // att, then f1
  for (int u = tid; u < 16 * 16; u += 512) {
    int row = u >> 4, c = u & 15;
    ((unsigned*)&yb[row][200])[c] = 0u;
    ((unsigned*)&fb[row][200])[c] = 0u;
  }

  // ---- S: scores rows m0..m0+15 vs all 48 K rows (3 tiles, K=224) ----
  for (int t = wv; t < 3; t += 8) {
    int n0 = t * 16;
    f4_t acc = mfma_tile<7>(q_bf + (m0 + col) * 224 + koff,
                            k_bf + (n0 + col) * 224 + koff);
    int gn = n0 + col;
#pragma unroll
    for (int r = 0; r < 4; ++r)
      tc[quad * 4 + r][gn] = acc[r] * 0.07071067811865475f;
  }
  __syncthreads();

  // ---- softmax rows (2 rows per wave), write P bf16 (pad-zeroed) ----
  for (int r = wv; r < 16; r += 8) {
    bool live = (m0 + r) < SS;
    float v = (lane < SS && live) ? tc[r][lane] : -__builtin_inff();
    float mx = v;
#pragma unroll
    for (int off = 32; off; off >>= 1) mx = fmaxf(mx, __shfl_xor(mx, off));
    float e = (lane < SS && live) ? __expf(v - mx) : 0.f;
    float sm = e;
#pragma unroll
    for (int off = 32; off; off >>= 1) sm += __shfl_xor(sm, off);
    Pb[r][lane] = (lane < SS && live) ? f2bf(e / sm) : (unsigned short)0;
  }
  __syncthreads();

  // ---- PV: att = P @ V  (13 tiles, K=64) -> fb bf16 ----
  for (int t = wv; t < 13; t += 8) {
    int n0 = t * 16;
    f4_t acc = mfma_tile_lds<2>(&Pb[0][0] + col * 72 + koff,
                                vt_bf + (n0 + col) * 64 + koff);
    int gn = n0 + col;
    if (gn < DM) {
#pragma unroll
      for (int r = 0; r < 4; ++r)
        fb[quad * 4 + r][gn] = f2bf(acc[r]);
    }
  }
  __syncthreads();

  // ---- A: y = x + att @ aout^T + b -> tc ----
  for (int t = wv; t < 13; t += 8) {
    int n0 = t * 16;
    f4_t acc = mfma_tile_lds<7>(&fb[0][0] + col * 232 + koff,
                                aout_wb + (size_t)(n0 + col) * 224 + koff);
    int gn = n0 + col;
    float bv = (gn < DM) ? aout_b[gn] : 0.f;
#pragma unroll
    for (int r = 0; r < 4; ++r) {
      int row = quad * 4 + r;
      float v = acc[r] + bv;
      if (gn < DM) v += x_f32[(m0 + row) * 208 + gn];
      tc[row][gn] = v;
    }
  }
  __syncthreads();

  // ---- LN1 -> tc (in place) + yb bf16 ----
  for (int r = wv; r < 16; r += 8) {
    float* p = &tc[r][0];
    float vals[4]; float s = 0.f;
#pragma unroll
    for (int i = 0; i < 4; ++i) { int k = lane + 64 * i; vals[i] = (k < DM) ? p[k] : 0.f; s += vals[i]; }
#pragma unroll
    for (int off = 32; off; off >>= 1) s += __shfl_xor(s, off);
    float mean = s * (1.f / DM);
    float vs = 0.f;
#pragma unroll
    for (int i = 0; i < 4; ++i) { int k = lane + 64 * i; if (k < DM) { float d = vals[i] - mean; vs += d * d; } }
#pragma unroll
    for (int off = 32; off; off >>= 1) vs += __shfl_xor(vs, off);
    float rstd = rsqrtf(vs * (1.f / DM) + 1e-5f);
#pragma unroll
    for (int i = 0; i < 4; ++i) {
      int k = lane + 64 * i;
      if (k < DM) {
        float o = (vals[i] - mean) * rstd * ln1_g[k] + ln1_b[k];
        p[k] = o;
        yb[r][k] = f2bf(o);
      }
    }
  }
  __syncthreads();

  // ---- C: f1 = relu(y @ lin1^T + b) -> fb (att dead) ----
  for (int t = wv; t < 13; t += 8) {
    int n0 = t * 16;
    f4_t acc = mfma_tile_lds<7>(&yb[0][0] + col * 232 + koff,
                                lin1_wb + (size_t)(n0 + col) * 224 + koff);
    int gn = n0 + col;
    if (gn < DM) {
      float bv = lin1_b[gn];
#pragma unroll
      for (int r = 0; r < 4; ++r)
        fb[quad * 4 + r][gn] = f2bf(fmaxf(acc[r] + bv, 0.f));
    }
  }
  __syncthreads();

  // ---- D: y2 = y + f1 @ lin2^T + b -> tc ----
  for (int t = wv; t < 13; t += 8) {
    int n0 = t * 16;
    f4_t acc = mfma_tile_lds<7>(&fb[0][0] + col * 232 + koff,
                                lin2_wb + (size_t)(n0 + col) * 224 + koff);
    int gn = n0 + col;
    if (gn < DM) {
      float bv = lin2_b[gn];
#pragma unroll
      for (int r = 0; r < 4; ++r) {
        int row = quad * 4 + r;
        tc[row][gn] = acc[r] + bv + tc[row][gn];
      }
    }
  }
  __syncthreads();

  // ---- LN2 -> global y2 ----
  for (int r = wv; r < 16; r += 8) {
    float* p = &tc[r][0];
    float vals[4]; float s = 0.f;
#pragma unroll
    for (int i = 0; i < 4; ++i) { int k = lane + 64 * i; vals[i] = (k < DM) ? p[k] : 0.f; s += vals[i]; }
#pragma unroll
    for (int off = 32; off; off >>= 1) s += __shfl_xor(s, off);
    float mean = s * (1.f / DM);
    float vs = 0.f;
#pragma unroll
    for (int i = 0; i < 4; ++i) { int k = lane + 64 * i; if (k < DM) { float d = vals[i] - mean; vs += d * d; } }
#pragma unroll
    for (int off = 32; off; off >>= 1) vs += __shfl_xor(vs, off);
    float rstd = rsqrtf(vs * (1.f / DM) + 1e-5f);
    int grow = m0 + r;
#pragma unroll
    for (int i = 0; i < 4; ++i) {
      int k = lane + 64 * i;
      if (k < DM) y2g[grow * 208 + k] = (vals[i] - mean) * rstd * ln2_g[k] + ln2_b[k];
    }
  }
}

// ---------------------------------------------------------------------------
// K3: classifier. One wave per (b, j).
// ---------------------------------------------------------------------------
__global__ __launch_bounds__(256) void k_cls(
    const char* __restrict__ scratch, const float* __restrict__ fcw,
    const float* __restrict__ fcb, float* __restrict__ out)
{
  int gw = blockIdx.x * 4 + (threadIdx.x >> 6);   // b*32 + j
  int lane = threadIdx.x & 63;
  int b = gw >> 5, j = gw & 31;
  const float* y2 = (const float*)(scratch + (size_t)b * SB_BLK + SB_Y2);
  const float* r0 = y2;
  const float* rj = y2 + (1 + j) * 208;
  float a0 = 0.f, a1 = 0.f;
  for (int k = lane; k < DM; k += 64) {
    float u = r0[k], w = rj[k];
    a0 += u * fcw[k]       + w * fcw[200 + k];
    a1 += u * fcw[400 + k] + w * fcw[600 + k];
  }
#pragma unroll
  for (int off = 32; off; off >>= 1) {
    a0 += __shfl_xor(a0, off);
    a1 += __shfl_xor(a1, off);
  }
  if (lane == 0) {
    out[gw * 2 + 0] = a0 + fcb[0];
    out[gw * 2 + 1] = a1 + fcb[1];
  }
}

// ---------------------------------------------------------------------------
extern "C" void kernel_launch(void* const* d_in, const int* in_sizes, int n_in,
                              void* d_out, int out_size, void* d_ws, size_t ws_size,
                              hipStream_t stream)
{
  (void)in_sizes; (void)n_in; (void)out_size; (void)ws_size;
  const float* hidden = (const float*)d_in[0];
  const int*   clause = (const int*)d_in[1];
  const float* fc5_w  = (const float*)d_in[2];
  const float* fc1_w  = (const float*)d_in[4];
  const float* fc1_b  = (const float*)d_in[5];
  const float* ain_w  = (const float*)d_in[6];
  const float* ain_b  = (const float*)d_in[7];
  const float* aout_w = (const float*)d_in[8];
  const float* aout_b = (const float*)d_in[9];
  const float* ln1_g  = (const float*)d_in[10];
  const float* ln1_b  = (const float*)d_in[11];
  const float* lin1_w = (const float*)d_in[12];
  const float* lin1_b = (const float*)d_in[13];
  const float* lin2_w = (const float*)d_in[14];
  const float* lin2_b = (const float*)d_in[15];
  const float* ln2_g  = (const float*)d_in[16];
  const float* ln2_b  = (const float*)d_in[17];
  const float* fc_w   = (const float*)d_in[18];
  const float* fc_b   = (const float*)d_in[19];
  float* out = (float*)d_out;

  char* w8 = (char*)d_ws;
  unsigned short* pooled_bf = (unsigned short*)(w8 + 0);  // [4224][768] + 32KB guard
  char* scratch = w8 + 6520832;                           // 128 * SB_BLK
  size_t wbase = 6520832 + (size_t)NB * SB_BLK;
  unsigned short* fc1_wb  = (unsigned short*)(w8 + wbase);
  unsigned short* ain_wb  = (unsigned short*)(w8 + wbase + 319488);
  unsigned short* aout_wb = (unsigned short*)(w8 + wbase + 591872);
  unsigned short* lin1_wb = (unsigned short*)(w8 + wbase + 685056);
  unsigned short* lin2_wb = (unsigned short*)(w8 + wbase + 778240);

  // 4224 pool blocks + 1187 convert/pad blocks
  pc_kernel<<<dim3(NB * SS + 1187), 512, 0, stream>>>(
      hidden, clause, fc5_w, pooled_bf,
      fc1_w, ain_w, aout_w, lin1_w, lin2_w,
      fc1_wb, ain_wb, aout_wb, lin1_wb, lin2_wb, scratch);
  k_fc1qkv<<<dim3(NB * 3), 512, 0, stream>>>(pooled_bf, fc1_wb, fc1_b,
      ain_wb, ain_b, scratch);
  k_postattn<<<dim3(NB * 3), 512, 0, stream>>>(aout_wb, aout_b, ln1_g, ln1_b,
      lin1_wb, lin1_b, lin2_wb, lin2_b, ln2_g, ln2_b, scratch);
  k_cls<<<dim3(1024), 256, 0, stream>>>(scratch, fc_w, fc_b, out);
}

// Round 3
// 367.566 us; speedup vs baseline: 1.1095x; 1.0193x over previous
//
#include <hip/hip_runtime.h>

#define NB 128
#define LL 512
#define DD 768
#define JJ 32
#define SS 33
#define DM 200

typedef __attribute__((ext_vector_type(8))) short bf8_t;   // 8 bf16 (4 VGPRs)
typedef __attribute__((ext_vector_type(4))) float f4_t;    // MFMA C/D

// per-batch scratch block (bytes)
#define SB_XF   0                 // x_f32 [48][208] f32
#define SB_QB   61440             // q_bf  [48][224]
#define SB_KB   82944             // k_bf  [48][224]
#define SB_VT   104448            // vt_bf [208][64]
#define SB_Y2   235520            // y2_f32[48][208] f32
#define SB_BLK  275456

static __device__ __forceinline__ unsigned short f2bf(float f) {
  unsigned u = __float_as_uint(f);
  return (unsigned short)((u + 0x7FFFu + ((u >> 16) & 1u)) >> 16);  // RNE
}

template<int KS>
static __device__ __forceinline__ f4_t mfma_tile(
    const unsigned short* pa, const unsigned short* pw)
{
  f4_t acc = {0.f, 0.f, 0.f, 0.f};
  bf8_t a = *(const bf8_t*)pa;
  bf8_t w = *(const bf8_t*)pw;
#pragma unroll
  for (int s = 1; s < KS; ++s) {
    bf8_t a2 = *(const bf8_t*)(pa + 32 * s);
    bf8_t w2 = *(const bf8_t*)(pw + 32 * s);
    acc = __builtin_amdgcn_mfma_f32_16x16x32_bf16(a, w, acc, 0, 0, 0);
    a = a2; w = w2;
  }
  acc = __builtin_amdgcn_mfma_f32_16x16x32_bf16(a, w, acc, 0, 0, 0);
  return acc;
}

template<int KS>
static __device__ __forceinline__ f4_t mfma_tile_lds(
    const unsigned short* pa, const unsigned short* pw)
{
  f4_t acc = {0.f, 0.f, 0.f, 0.f};
#pragma unroll
  for (int s = 0; s < KS; ++s) {
    bf8_t a = *(const bf8_t*)(pa + 32 * s);
    bf8_t w = *(const bf8_t*)(pw + 32 * s);
    acc = __builtin_amdgcn_mfma_f32_16x16x32_bf16(a, w, acc, 0, 0, 0);
  }
  return acc;
}

// ---------------------------------------------------------------------------
// PC kernel: blocks [0, 4224) = fused pool (single HBM read, register-staged
// rows + cross-wave LDS partial reduction); blocks [4224, ...) = weight
// convert + scratch pad-zero.
// ---------------------------------------------------------------------------
__global__ __launch_bounds__(512, 4) void pc_kernel(
    const float* __restrict__ hidden, const int* __restrict__ clause,
    const float* __restrict__ fc5w, unsigned short* __restrict__ pooled_bf,
    const float* __restrict__ fc1_w, const float* __restrict__ ain_w,
    const float* __restrict__ aout_w, const float* __restrict__ lin1_w,
    const float* __restrict__ lin2_w,
    unsigned short* __restrict__ fc1_wb, unsigned short* __restrict__ ain_wb,
    unsigned short* __restrict__ aout_wb, unsigned short* __restrict__ lin1_wb,
    unsigned short* __restrict__ lin2_wb, char* __restrict__ scratch)
{
  const int tid = threadIdx.x;
  if (blockIdx.x >= NB * SS) {
    int t = (blockIdx.x - NB * SS) * 512 + tid;
    if (t < 208 * 768) {
      int n = t / 768, k = t - n * 768;
      fc1_wb[t] = f2bf((n < 200) ? fc1_w[n * 768 + k] : 0.f);
      return;
    }
    t -= 208 * 768;
    if (t < 608 * 224) {
      int n = t / 224, k = t - n * 224;
      ain_wb[t] = f2bf((n < 600 && k < 200) ? ain_w[n * 200 + k] : 0.f);
      return;
    }
    t -= 608 * 224;
    if (t < 208 * 224) {
      int n = t / 224, k = t - n * 224;
      aout_wb[t] = f2bf((n < 200 && k < 200) ? aout_w[n * 200 + k] : 0.f);
      return;
    }
    t -= 208 * 224;
    if (t < 208 * 224) {
      int n = t / 224, k = t - n * 224;
      lin1_wb[t] = f2bf((n < 200 && k < 200) ? lin1_w[n * 200 + k] : 0.f);
      return;
    }
    t -= 208 * 224;
    if (t < 208 * 224) {
      int n = t / 224, k = t - n * 224;
      lin2_wb[t] = f2bf((n < 200 && k < 200) ? lin2_w[n * 200 + k] : 0.f);
      return;
    }
    t -= 208 * 224;
    if (t < NB * 1344) {          // pad-zero: QB/KB cols 192-223, VT cols 32-63
      int b = t / 1344, r = t - b * 1344;
      char* sb = scratch + (size_t)b * SB_BLK;
      const uint4 z = make_uint4(0, 0, 0, 0);
      if (r < 384) {
        int bi = r / 192, rr = r - bi * 192;
        int row = rr >> 2, c = rr & 3;
        int off = (bi == 0) ? SB_QB : SB_KB;
        *(uint4*)((unsigned short*)(sb + off) + row * 224 + 192 + c * 8) = z;
      } else {
        int rr = r - 384;
        int row = rr >> 2, c = rr & 3;
        *(uint4*)((unsigned short*)(sb + SB_VT) + row * 64 + 32 + c * 8) = z;
      }
    }
    return;
  }

  // -------- pool part: block = (b, s); hidden read from HBM exactly once ---
  int blk = blockIdx.x;
  int b = blk / SS;
  int s = blk - b * SS;
  int t0 = (s == 0) ? 0 : clause[b * JJ + s - 1];
  int t1 = (s == JJ) ? LL : clause[b * JJ + s];
  int nt = t1 - t0;
  if (nt > 64) nt = 64;
  if (nt < 1) nt = 1;

  __shared__ float wsm[64];
  __shared__ __align__(16) float pw[8][772];   // per-wave partials, 4-bank row shift
  int wave = tid >> 6, lane = tid & 63;

  const float4* w4 = (const float4*)fc5w;
  float4 wa = w4[lane], wwb = w4[lane + 64], wc = w4[lane + 128];

  // pass 1: each wave owns rows {wave, wave+8, wave+16, wave+24}; keep row
  // data in registers while computing the score.
  float4 hv[4][3];
#pragma unroll
  for (int i = 0; i < 4; ++i) {
    int r = wave + 8 * i;
    if (r < nt) {
      const float4* hp = (const float4*)(hidden + ((long long)b * LL + t0 + r) * DD);
      float4 h0 = hp[lane], h1 = hp[lane + 64], h2 = hp[lane + 128];
      hv[i][0] = h0; hv[i][1] = h1; hv[i][2] = h2;
      float acc = h0.x*wa.x + h0.y*wa.y + h0.z*wa.z + h0.w*wa.w
                + h1.x*wwb.x + h1.y*wwb.y + h1.z*wwb.z + h1.w*wwb.w
                + h2.x*wc.x + h2.y*wc.y + h2.z*wc.z + h2.w*wc.w;
#pragma unroll
      for (int off = 32; off; off >>= 1) acc += __shfl_xor(acc, off);
      if (lane == 0) wsm[r] = acc;
    }
  }
  // fallback scores for rows >= 32 (never taken for this generator; correct anyway)
  for (int r = wave + 32; r < nt; r += 8) {
    const float4* hp = (const float4*)(hidden + ((long long)b * LL + t0 + r) * DD);
    float4 h0 = hp[lane], h1 = hp[lane + 64], h2 = hp[lane + 128];
    float acc = h0.x*wa.x + h0.y*wa.y + h0.z*wa.z + h0.w*wa.w
              + h1.x*wwb.x + h1.y*wwb.y + h1.z*wwb.z + h1.w*wwb.w
              + h2.x*wc.x + h2.y*wc.y + h2.z*wc.z + h2.w*wc.w;
#pragma unroll
    for (int off = 32; off; off >>= 1) acc += __shfl_xor(acc, off);
    if (lane == 0) wsm[r] = acc;
  }
  __syncthreads();

  // softmax over scores (wave 0)
  if (wave == 0) {
    float v = (lane < nt) ? wsm[lane] : -__builtin_inff();
    float mx = v;
#pragma unroll
    for (int off = 32; off; off >>= 1) mx = fmaxf(mx, __shfl_xor(mx, off));
    float e = (lane < nt) ? __expf(v - mx) : 0.f;
    float sm = e;
#pragma unroll
    for (int off = 32; off; off >>= 1) sm += __shfl_xor(sm, off);
    if (lane < nt) wsm[lane] = e / sm;
  }
  __syncthreads();

  // pass 2: per-wave weighted partial from registers
  float4 p0 = {0,0,0,0}, p1 = {0,0,0,0}, p2 = {0,0,0,0};
#pragma unroll
  for (int i = 0; i < 4; ++i) {
    int r = wave + 8 * i;
    if (r < nt) {
      float w = wsm[r];
      p0.x = fmaf(w, hv[i][0].x, p0.x); p0.y = fmaf(w, hv[i][0].y, p0.y);
      p0.z = fmaf(w, hv[i][0].z, p0.z); p0.w = fmaf(w, hv[i][0].w, p0.w);
      p1.x = fmaf(w, hv[i][1].x, p1.x); p1.y = fmaf(w, hv[i][1].y, p1.y);
      p1.z = fmaf(w, hv[i][1].z, p1.z); p1.w = fmaf(w, hv[i][1].w, p1.w);
      p2.x = fmaf(w, hv[i][2].x, p2.x); p2.y = fmaf(w, hv[i][2].y, p2.y);
      p2.z = fmaf(w, hv[i][2].z, p2.z); p2.w = fmaf(w, hv[i][2].w, p2.w);
    }
  }
  // fallback accumulate for rows >= 32 (global re-read; dead in practice)
  for (int r = wave + 32; r < nt; r += 8) {
    const float4* hp = (const float4*)(hidden + ((long long)b * LL + t0 + r) * DD);
    float w = wsm[r];
    float4 h0 = hp[lane], h1 = hp[lane + 64], h2 = hp[lane + 128];
    p0.x = fmaf(w, h0.x, p0.x); p0.y = fmaf(w, h0.y, p0.y);
    p0.z = fmaf(w, h0.z, p0.z); p0.w = fmaf(w, h0.w, p0.w);
    p1.x = fmaf(w, h1.x, p1.x); p1.y = fmaf(w, h1.y, p1.y);
    p1.z = fmaf(w, h1.z, p1.z); p1.w = fmaf(w, h1.w, p1.w);
    p2.x = fmaf(w, h2.x, p2.x); p2.y = fmaf(w, h2.y, p2.y);
    p2.z = fmaf(w, h2.z, p2.z); p2.w = fmaf(w, h2.w, p2.w);
  }
  {
    float4* pp = (float4*)&pw[wave][0];
    pp[lane] = p0; pp[lane + 64] = p1; pp[lane + 128] = p2;
  }
  __syncthreads();

  // pass 3: reduce 8 partials, store bf16
  if (tid < 384) {
    float2 acc = make_float2(0.f, 0.f);
#pragma unroll
    for (int w = 0; w < 8; ++w) {
      float2 v = *(const float2*)&pw[w][tid * 2];
      acc.x += v.x; acc.y += v.y;
    }
    ushort2 o;
    o.x = f2bf(acc.x); o.y = f2bf(acc.y);
    *(ushort2*)(pooled_bf + (long long)blk * DD + tid * 2) = o;
  }
}

// ---------------------------------------------------------------------------
// K1: per (b, mt), 512 thr: stage A-tile (16 pooled rows) in LDS, then
// x = pooled@fc1^T + b (13 tiles, x -> LDS+global), qkv = x@ain^T + b
// (38 tiles) routed to q/k/vt scratch.
// ---------------------------------------------------------------------------
__global__ __launch_bounds__(512, 4) void k_fc1qkv(
    const unsigned short* __restrict__ pooled,
    const unsigned short* __restrict__ fc1_wb, const float* __restrict__ fc1_b,
    const unsigned short* __restrict__ ain_wb, const float* __restrict__ ain_b,
    char* __restrict__ scratch)
{
  const int b = blockIdx.x / 3, mt = blockIdx.x % 3, m0 = mt * 16;
  const int tid = threadIdx.x, wv = tid >> 6, lane = tid & 63;
  const int col = lane & 15, quad = lane >> 4, koff = quad * 8;

  char* sb = scratch + (size_t)b * SB_BLK;
  float* x_f32 = (float*)(sb + SB_XF);
  unsigned short* q_bf  = (unsigned short*)(sb + SB_QB);
  unsigned short* k_bf  = (unsigned short*)(sb + SB_KB);
  unsigned short* vt_bf = (unsigned short*)(sb + SB_VT);

  __shared__ __align__(16) unsigned short sA[16][776];  // stride 776: row shift 4 banks
  __shared__ __align__(16) unsigned short xb[16][232];

  // stage A-tile: 16 rows x 768 bf16 (row src clamped to 32 for dead rows)
  {
    int r = tid >> 5, c = tid & 31;
    int src = m0 + r; if (src > 32) src = 32;
    const unsigned* gp = (const unsigned*)(pooled + (size_t)(b * SS + src) * DD);
    unsigned* lp = (unsigned*)&sA[r][0];
#pragma unroll
    for (int i = 0; i < 12; ++i) lp[c + 32 * i] = gp[c + 32 * i];
  }
  for (int u = tid; u < 16 * 16; u += 512) {
    int row = u >> 4, c = u & 15;
    ((unsigned*)&xb[row][200])[c] = 0u;
  }
  __syncthreads();

  for (int t = wv; t < 13; t += 8) {
    int n0 = t * 16;
    f4_t acc = mfma_tile_lds<24>(&sA[0][0] + col * 776 + koff,
                                 fc1_wb + (size_t)(n0 + col) * DD + koff);
    int gn = n0 + col;
    if (gn < DM) {
      float bv = fc1_b[gn];
#pragma unroll
      for (int r = 0; r < 4; ++r) {
        int row = quad * 4 + r;
        float v = acc[r] + bv;
        x_f32[(m0 + row) * 208 + gn] = v;
        xb[row][gn] = f2bf(v);
      }
    }
  }
  __syncthreads();

  for (int t = wv; t < 38; t += 8) {
    int n0 = t * 16;
    f4_t acc = mfma_tile_lds<7>(&xb[0][0] + col * 232 + koff,
                                ain_wb + (size_t)(n0 + col) * 224 + koff);
    int gn = n0 + col;
    if (gn < 600) {
      float bv = ain_b[gn];
#pragma unroll
      for (int r = 0; r < 4; ++r) {
        int gm = m0 + quad * 4 + r;
        unsigned short bfv = f2bf(acc[r] + bv);
        if (gn < 200)      q_bf[gm * 224 + gn] = bfv;
        else if (gn < 400) k_bf[gm * 224 + (gn - 200)] = bfv;
        else if (gm < SS)  vt_bf[(gn - 400) * 64 + gm] = bfv;   // V^T
      }
    }
  }
}

// ---------------------------------------------------------------------------
// K2: per (b, mt), 512 thr: 16 own Q-rows through attention + aout + LN1 +
// FFN + LN2, all intermediates in LDS. y2 -> global scratch.
// ---------------------------------------------------------------------------
__global__ __launch_bounds__(512, 4) void k_postattn(
    const unsigned short* __restrict__ aout_wb, const float* __restrict__ aout_b,
    const float* __restrict__ ln1_g, const float* __restrict__ ln1_b,
    const unsigned short* __restrict__ lin1_wb, const float* __restrict__ lin1_b,
    const unsigned short* __restrict__ lin2_wb, const float* __restrict__ lin2_b,
    const float* __restrict__ ln2_g, const float* __restrict__ ln2_b,
    char* __restrict__ scratch)
{
  const int b = blockIdx.x / 3, mt = blockIdx.x % 3, m0 = mt * 16;
  const int tid = threadIdx.x, wv = tid >> 6, lane = tid & 63;
  const int col = lane & 15, quad = lane >> 4, koff = quad * 8;

  char* sb = scratch + (size_t)b * SB_BLK;
  const unsigned short* q_bf  = (const unsigned short*)(sb + SB_QB);
  const unsigned short* k_bf  = (const unsigned short*)(sb + SB_KB);
  const unsigned short* vt_bf = (const unsigned short*)(sb + SB_VT);
  const float* x_f32 = (const float*)(sb + SB_XF);
  float* y2g = (float*)(sb + SB_Y2);

  __shared__ float tc[16][211];                         // scores then C-tile
  __shared__ __align__(16) unsigned short Pb[16][72];   // softmax(P) bf16
  __shared__ __align__(16) unsigned short yb[16][232];  // LN1 out bf16
  __shared__ __align__(16) unsigned short fb[16][232];  // att, then f1
  for (int u = tid; u < 16 * 16; u += 512) {
    int row = u >> 4, c = u & 15;
    ((unsigned*)&yb[row][200])[c] = 0u;
    ((unsigned*)&fb[row][200])[c] = 0u;
  }

  // ---- S: scores rows m0..m0+15 vs all 48 K rows (3 tiles, K=224) ----
  for (int t = wv; t < 3; t += 8) {
    int n0 = t * 16;
    f4_t acc = mfma_tile<7>(q_bf + (m0 + col) * 224 + koff,
                            k_bf + (n0 + col) * 224 + koff);
    int gn = n0 + col;
#pragma unroll
    for (int r = 0; r < 4; ++r)
      tc[quad * 4 + r][gn] = acc[r] * 0.07071067811865475f;
  }
  __syncthreads();

  // ---- softmax rows (2 rows per wave), write P bf16 (pad-zeroed) ----
  for (int r = wv; r < 16; r += 8) {
    bool live = (m0 + r) < SS;
    float v = (lane < SS && live) ? tc[r][lane] : -__builtin_inff();
    float mx = v;
#pragma unroll
    for (int off = 32; off; off >>= 1) mx = fmaxf(mx, __shfl_xor(mx, off));
    float e = (lane < SS && live) ? __expf(v - mx) : 0.f;
    float sm = e;
#pragma unroll
    for (int off = 32; off; off >>= 1) sm += __shfl_xor(sm, off);
    Pb[r][lane] = (lane < SS && live) ? f2bf(e / sm) : (unsigned short)0;
  }
  __syncthreads();

  // ---- PV: att = P @ V  (13 tiles, K=64) -> fb bf16 ----
  for (int t = wv; t < 13; t += 8) {
    int n0 = t * 16;
    f4_t acc = mfma_tile_lds<2>(&Pb[0][0] + col * 72 + koff,
                                vt_bf + (n0 + col) * 64 + koff);
    int gn = n0 + col;
    if (gn < DM) {
#pragma unroll
      for (int r = 0; r < 4; ++r)
        fb[quad * 4 + r][gn] = f2bf(acc[r]);
    }
  }
  __syncthreads();

  // ---- A: y = x + att @ aout^T + b -> tc ----
  for (int t = wv; t < 13; t += 8) {
    int n0 = t * 16;
    f4_t acc = mfma_tile_lds<7>(&fb[0][0] + col * 232 + koff,
                                aout_wb + (size_t)(n0 + col) * 224 + koff);
    int gn = n0 + col;
    float bv = (gn < DM) ? aout_b[gn] : 0.f;
#pragma unroll
    for (int r = 0; r < 4; ++r) {
      int row = quad * 4 + r;
      float v = acc[r] + bv;
      if (gn < DM) v += x_f32[(m0 + row) * 208 + gn];
      tc[row][gn] = v;
    }
  }
  __syncthreads();

  // ---- LN1 -> tc (in place) + yb bf16 ----
  for (int r = wv; r < 16; r += 8) {
    float* p = &tc[r][0];
    float vals[4]; float s = 0.f;
#pragma unroll
    for (int i = 0; i < 4; ++i) { int k = lane + 64 * i; vals[i] = (k < DM) ? p[k] : 0.f; s += vals[i]; }
#pragma unroll
    for (int off = 32; off; off >>= 1) s += __shfl_xor(s, off);
    float mean = s * (1.f / DM);
    float vs = 0.f;
#pragma unroll
    for (int i = 0; i < 4; ++i) { int k = lane + 64 * i; if (k < DM) { float d = vals[i] - mean; vs += d * d; } }
#pragma unroll
    for (int off = 32; off; off >>= 1) vs += __shfl_xor(vs, off);
    float rstd = rsqrtf(vs * (1.f / DM) + 1e-5f);
#pragma unroll
    for (int i = 0; i < 4; ++i) {
      int k = lane + 64 * i;
      if (k < DM) {
        float o = (vals[i] - mean) * rstd * ln1_g[k] + ln1_b[k];
        p[k] = o;
        yb[r][k] = f2bf(o);
      }
    }
  }
  __syncthreads();

  // ---- C: f1 = relu(y @ lin1^T + b) -> fb (att dead) ----
  for (int t = wv; t < 13; t += 8) {
    int n0 = t * 16;
    f4_t acc = mfma_tile_lds<7>(&yb[0][0] + col * 232 + koff,
                                lin1_wb + (size_t)(n0 + col) * 224 + koff);
    int gn = n0 + col;
    if (gn < DM) {
      float bv = lin1_b[gn];
#pragma unroll
      for (int r = 0; r < 4; ++r)
        fb[quad * 4 + r][gn] = f2bf(fmaxf(acc[r] + bv, 0.f));
    }
  }
  __syncthreads();

  // ---- D: y2 = y + f1 @ lin2^T + b -> tc ----
  for (int t = wv; t < 13; t += 8) {
    int n0 = t * 16;
    f4_t acc = mfma_tile_lds<7>(&fb[0][0] + col * 232 + koff,
                                lin2_wb + (size_t)(n0 + col) * 224 + koff);
    int gn = n0 + col;
    if (gn < DM) {
      float bv = lin2_b[gn];
#pragma unroll
      for (int r = 0; r < 4; ++r) {
        int row = quad * 4 + r;
        tc[row][gn] = acc[r] + bv + tc[row][gn];
      }
    }
  }
  __syncthreads();

  // ---- LN2 -> global y2 ----
  for (int r = wv; r < 16; r += 8) {
    float* p = &tc[r][0];
    float vals[4]; float s = 0.f;
#pragma unroll
    for (int i = 0; i < 4; ++i) { int k = lane + 64 * i; vals[i] = (k < DM) ? p[k] : 0.f; s += vals[i]; }
#pragma unroll
    for (int off = 32; off; off >>= 1) s += __shfl_xor(s, off);
    float mean = s * (1.f / DM);
    float vs = 0.f;
#pragma unroll
    for (int i = 0; i < 4; ++i) { int k = lane + 64 * i; if (k < DM) { float d = vals[i] - mean; vs += d * d; } }
#pragma unroll
    for (int off = 32; off; off >>= 1) vs += __shfl_xor(vs, off);
    float rstd = rsqrtf(vs * (1.f / DM) + 1e-5f);
    int grow = m0 + r;
#pragma unroll
    for (int i = 0; i < 4; ++i) {
      int k = lane + 64 * i;
      if (k < DM) y2g[grow * 208 + k] = (vals[i] - mean) * rstd * ln2_g[k] + ln2_b[k];
    }
  }
}

// ---------------------------------------------------------------------------
// K3: classifier. One wave per (b, j).
// ---------------------------------------------------------------------------
__global__ __launch_bounds__(256) void k_cls(
    const char* __restrict__ scratch, const float* __restrict__ fcw,
    const float* __restrict__ fcb, float* __restrict__ out)
{
  int gw = blockIdx.x * 4 + (threadIdx.x >> 6);   // b*32 + j
  int lane = threadIdx.x & 63;
  int b = gw >> 5, j = gw & 31;
  const float* y2 = (const float*)(scratch + (size_t)b * SB_BLK + SB_Y2);
  const float* r0 = y2;
  const float* rj = y2 + (1 + j) * 208;
  float a0 = 0.f, a1 = 0.f;
  for (int k = lane; k < DM; k += 64) {
    float u = r0[k], w = rj[k];
    a0 += u * fcw[k]       + w * fcw[200 + k];
    a1 += u * fcw[400 + k] + w * fcw[600 + k];
  }
#pragma unroll
  for (int off = 32; off; off >>= 1) {
    a0 += __shfl_xor(a0, off);
    a1 += __shfl_xor(a1, off);
  }
  if (lane == 0) {
    out[gw * 2 + 0] = a0 + fcb[0];
    out[gw * 2 + 1] = a1 + fcb[1];
  }
}

// ---------------------------------------------------------------------------
extern "C" void kernel_launch(void* const* d_in, const int* in_sizes, int n_in,
                              void* d_out, int out_size, void* d_ws, size_t ws_size,
                              hipStream_t stream)
{
  (void)in_sizes; (void)n_in; (void)out_size; (void)ws_size;
  const float* hidden = (const float*)d_in[0];
  const int*   clause = (const int*)d_in[1];
  const float* fc5_w  = (const float*)d_in[2];
  const float* fc1_w  = (const float*)d_in[4];
  const float* fc1_b  = (const float*)d_in[5];
  const float* ain_w  = (const float*)d_in[6];
  const float* ain_b  = (const float*)d_in[7];
  const float* aout_w = (const float*)d_in[8];
  const float* aout_b = (const float*)d_in[9];
  const float* ln1_g  = (const float*)d_in[10];
  const float* ln1_b  = (const float*)d_in[11];
  const float* lin1_w = (const float*)d_in[12];
  const float* lin1_b = (const float*)d_in[13];
  const float* lin2_w = (const float*)d_in[14];
  const float* lin2_b = (const float*)d_in[15];
  const float* ln2_g  = (const float*)d_in[16];
  const float* ln2_b  = (const float*)d_in[17];
  const float* fc_w   = (const float*)d_in[18];
  const float* fc_b   = (const float*)d_in[19];
  float* out = (float*)d_out;

  char* w8 = (char*)d_ws;
  unsigned short* pooled_bf = (unsigned short*)(w8 + 0);  // [4224][768] + 32KB guard
  char* scratch = w8 + 6520832;                           // 128 * SB_BLK
  size_t wbase = 6520832 + (size_t)NB * SB_BLK;
  unsigned short* fc1_wb  = (unsigned short*)(w8 + wbase);
  unsigned short* ain_wb  = (unsigned short*)(w8 + wbase + 319488);
  unsigned short* aout_wb = (unsigned short*)(w8 + wbase + 591872);
  unsigned short* lin1_wb = (unsigned short*)(w8 + wbase + 685056);
  unsigned short* lin2_wb = (unsigned short*)(w8 + wbase + 778240);

  // 4224 pool blocks + 1187 convert/pad blocks
  pc_kernel<<<dim3(NB * SS + 1187), 512, 0, stream>>>(
      hidden, clause, fc5_w, pooled_bf,
      fc1_w, ain_w, aout_w, lin1_w, lin2_w,
      fc1_wb, ain_wb, aout_wb, lin1_wb, lin2_wb, scratch);
  k_fc1qkv<<<dim3(NB * 3), 512, 0, stream>>>(pooled_bf, fc1_wb, fc1_b,
      ain_wb, ain_b, scratch);
  k_postattn<<<dim3(NB * 3), 512, 0, stream>>>(aout_wb, aout_b, ln1_g, ln1_b,
      lin1_wb, lin1_b, lin2_wb, lin2_b, ln2_g, ln2_b, scratch);
  k_cls<<<dim3(1024), 256, 0, stream>>>(scratch, fc_w, fc_b, out);
}

// Round 5
// 360.944 us; speedup vs baseline: 1.1298x; 1.0183x over previous
//
#include <hip/hip_runtime.h>

#define NB 128
#define LL 512
#define DD 768
#define JJ 32
#define SS 33
#define DM 200

typedef __attribute__((ext_vector_type(8))) short bf8_t;   // 8 bf16 (4 VGPRs)
typedef __attribute__((ext_vector_type(4))) float f4_t;    // MFMA C/D

// per-batch scratch block (bytes)
#define SB_XF   0                 // x_f32 [48][208] f32
#define SB_QB   61440             // q_bf  [48][224]
#define SB_KB   82944             // k_bf  [48][224]
#define SB_VT   104448            // vt_bf [208][64]
#define SB_BLK  131072

static __device__ __forceinline__ unsigned short f2bf(float f) {
  unsigned u = __float_as_uint(f);
  return (unsigned short)((u + 0x7FFFu + ((u >> 16) & 1u)) >> 16);  // RNE
}

template<int KS>
static __device__ __forceinline__ f4_t mfma_tile(
    const unsigned short* pa, const unsigned short* pw)
{
  f4_t acc = {0.f, 0.f, 0.f, 0.f};
  bf8_t a = *(const bf8_t*)pa;
  bf8_t w = *(const bf8_t*)pw;
#pragma unroll
  for (int s = 1; s < KS; ++s) {
    bf8_t a2 = *(const bf8_t*)(pa + 32 * s);
    bf8_t w2 = *(const bf8_t*)(pw + 32 * s);
    acc = __builtin_amdgcn_mfma_f32_16x16x32_bf16(a, w, acc, 0, 0, 0);
    a = a2; w = w2;
  }
  acc = __builtin_amdgcn_mfma_f32_16x16x32_bf16(a, w, acc, 0, 0, 0);
  return acc;
}

template<int KS>
static __device__ __forceinline__ f4_t mfma_tile_lds(
    const unsigned short* pa, const unsigned short* pw)
{
  f4_t acc = {0.f, 0.f, 0.f, 0.f};
#pragma unroll
  for (int s = 0; s < KS; ++s) {
    bf8_t a = *(const bf8_t*)(pa + 32 * s);
    bf8_t w = *(const bf8_t*)(pw + 32 * s);
    acc = __builtin_amdgcn_mfma_f32_16x16x32_bf16(a, w, acc, 0, 0, 0);
  }
  return acc;
}

// ---------------------------------------------------------------------------
// PC kernel: blocks [0, 4224) = fused pool (single HBM read, register-staged
// rows, loads-first for max MLP); blocks [4224, ...) = weight convert +
// scratch pad-zero.
// ---------------------------------------------------------------------------
__global__ __launch_bounds__(512, 4) void pc_kernel(
    const float* __restrict__ hidden, const int* __restrict__ clause,
    const float* __restrict__ fc5w, unsigned short* __restrict__ pooled_bf,
    const float* __restrict__ fc1_w, const float* __restrict__ ain_w,
    const float* __restrict__ aout_w, const float* __restrict__ lin1_w,
    const float* __restrict__ lin2_w,
    unsigned short* __restrict__ fc1_wb, unsigned short* __restrict__ ain_wb,
    unsigned short* __restrict__ aout_wb, unsigned short* __restrict__ lin1_wb,
    unsigned short* __restrict__ lin2_wb, char* __restrict__ scratch)
{
  const int tid = threadIdx.x;
  if (blockIdx.x >= NB * SS) {
    int t = (blockIdx.x - NB * SS) * 512 + tid;
    if (t < 208 * 768) {
      int n = t / 768, k = t - n * 768;
      fc1_wb[t] = f2bf((n < 200) ? fc1_w[n * 768 + k] : 0.f);
      return;
    }
    t -= 208 * 768;
    if (t < 608 * 224) {
      int n = t / 224, k = t - n * 224;
      ain_wb[t] = f2bf((n < 600 && k < 200) ? ain_w[n * 200 + k] : 0.f);
      return;
    }
    t -= 608 * 224;
    if (t < 208 * 224) {
      int n = t / 224, k = t - n * 224;
      aout_wb[t] = f2bf((n < 200 && k < 200) ? aout_w[n * 200 + k] : 0.f);
      return;
    }
    t -= 208 * 224;
    if (t < 208 * 224) {
      int n = t / 224, k = t - n * 224;
      lin1_wb[t] = f2bf((n < 200 && k < 200) ? lin1_w[n * 200 + k] : 0.f);
      return;
    }
    t -= 208 * 224;
    if (t < 208 * 224) {
      int n = t / 224, k = t - n * 224;
      lin2_wb[t] = f2bf((n < 200 && k < 200) ? lin2_w[n * 200 + k] : 0.f);
      return;
    }
    t -= 208 * 224;
    if (t < NB * 1344) {          // pad-zero: QB/KB cols 192-223, VT cols 32-63
      int b = t / 1344, r = t - b * 1344;
      char* sb = scratch + (size_t)b * SB_BLK;
      const uint4 z = make_uint4(0, 0, 0, 0);
      if (r < 384) {
        int bi = r / 192, rr = r - bi * 192;
        int row = rr >> 2, c = rr & 3;
        int off = (bi == 0) ? SB_QB : SB_KB;
        *(uint4*)((unsigned short*)(sb + off) + row * 224 + 192 + c * 8) = z;
      } else {
        int rr = r - 384;
        int row = rr >> 2, c = rr & 3;
        if (row < 208)   // vt_bf has exactly 208 rows; do NOT spill past block
          *(uint4*)((unsigned short*)(sb + SB_VT) + row * 64 + 32 + c * 8) = z;
      }
    }
    return;
  }

  // -------- pool part: block = (b, s); hidden read from HBM exactly once ---
  int blk = blockIdx.x;
  int b = blk / SS;
  int s = blk - b * SS;
  int t0 = (s == 0) ? 0 : clause[b * JJ + s - 1];
  int t1 = (s == JJ) ? LL : clause[b * JJ + s];
  int nt = t1 - t0;
  if (nt > 64) nt = 64;
  if (nt < 1) nt = 1;

  __shared__ float wsm[64];
  __shared__ __align__(16) float pw[8][772];   // per-wave partials, 4-bank row shift
  int wave = tid >> 6, lane = tid & 63;

  const float4* w4 = (const float4*)fc5w;
  float4 wa = w4[lane], wwb = w4[lane + 64], wc = w4[lane + 128];

  // pass 1a: issue ALL loads for owned rows first (max memory-level parallelism)
  float4 hv[4][3];
#pragma unroll
  for (int i = 0; i < 4; ++i) {
    int r = wave + 8 * i;
    if (r < nt) {
      const float4* hp = (const float4*)(hidden + ((long long)b * LL + t0 + r) * DD);
      hv[i][0] = hp[lane]; hv[i][1] = hp[lane + 64]; hv[i][2] = hp[lane + 128];
    }
  }
  // pass 1b: per-row score + wave reduce
#pragma unroll
  for (int i = 0; i < 4; ++i) {
    int r = wave + 8 * i;
    if (r < nt) {
      float4 h0 = hv[i][0], h1 = hv[i][1], h2 = hv[i][2];
      float acc = h0.x*wa.x + h0.y*wa.y + h0.z*wa.z + h0.w*wa.w
                + h1.x*wwb.x + h1.y*wwb.y + h1.z*wwb.z + h1.w*wwb.w
                + h2.x*wc.x + h2.y*wc.y + h2.z*wc.z + h2.w*wc.w;
#pragma unroll
      for (int off = 32; off; off >>= 1) acc += __shfl_xor(acc, off);
      if (lane == 0) wsm[r] = acc;
    }
  }
  // fallback scores for rows >= 32 (never taken for this generator; correct anyway)
  for (int r = wave + 32; r < nt; r += 8) {
    const float4* hp = (const float4*)(hidden + ((long long)b * LL + t0 + r) * DD);
    float4 h0 = hp[lane], h1 = hp[lane + 64], h2 = hp[lane + 128];
    float acc = h0.x*wa.x + h0.y*wa.y + h0.z*wa.z + h0.w*wa.w
              + h1.x*wwb.x + h1.y*wwb.y + h1.z*wwb.z + h1.w*wwb.w
              + h2.x*wc.x + h2.y*wc.y + h2.z*wc.z + h2.w*wc.w;
#pragma unroll
    for (int off = 32; off; off >>= 1) acc += __shfl_xor(acc, off);
    if (lane == 0) wsm[r] = acc;
  }
  __syncthreads();

  // softmax over scores (wave 0)
  if (wave == 0) {
    float v = (lane < nt) ? wsm[lane] : -__builtin_inff();
    float mx = v;
#pragma unroll
    for (int off = 32; off; off >>= 1) mx = fmaxf(mx, __shfl_xor(mx, off));
    float e = (lane < nt) ? __expf(v - mx) : 0.f;
    float sm = e;
#pragma unroll
    for (int off = 32; off; off >>= 1) sm += __shfl_xor(sm, off);
    if (lane < nt) wsm[lane] = e / sm;
  }
  __syncthreads();

  // pass 2: per-wave weighted partial from registers
  float4 p0 = {0,0,0,0}, p1 = {0,0,0,0}, p2 = {0,0,0,0};
#pragma unroll
  for (int i = 0; i < 4; ++i) {
    int r = wave + 8 * i;
    if (r < nt) {
      float w = wsm[r];
      p0.x = fmaf(w, hv[i][0].x, p0.x); p0.y = fmaf(w, hv[i][0].y, p0.y);
      p0.z = fmaf(w, hv[i][0].z, p0.z); p0.w = fmaf(w, hv[i][0].w, p0.w);
      p1.x = fmaf(w, hv[i][1].x, p1.x); p1.y = fmaf(w, hv[i][1].y, p1.y);
      p1.z = fmaf(w, hv[i][1].z, p1.z); p1.w = fmaf(w, hv[i][1].w, p1.w);
      p2.x = fmaf(w, hv[i][2].x, p2.x); p2.y = fmaf(w, hv[i][2].y, p2.y);
      p2.z = fmaf(w, hv[i][2].z, p2.z); p2.w = fmaf(w, hv[i][2].w, p2.w);
    }
  }
  // fallback accumulate for rows >= 32 (global re-read; dead in practice)
  for (int r = wave + 32; r < nt; r += 8) {
    const float4* hp = (const float4*)(hidden + ((long long)b * LL + t0 + r) * DD);
    float w = wsm[r];
    float4 h0 = hp[lane], h1 = hp[lane + 64], h2 = hp[lane + 128];
    p0.x = fmaf(w, h0.x, p0.x); p0.y = fmaf(w, h0.y, p0.y);
    p0.z = fmaf(w, h0.z, p0.z); p0.w = fmaf(w, h0.w, p0.w);
    p1.x = fmaf(w, h1.x, p1.x); p1.y = fmaf(w, h1.y, p1.y);
    p1.z = fmaf(w, h1.z, p1.z); p1.w = fmaf(w, h1.w, p1.w);
    p2.x = fmaf(w, h2.x, p2.x); p2.y = fmaf(w, h2.y, p2.y);
    p2.z = fmaf(w, h2.z, p2.z); p2.w = fmaf(w, h2.w, p2.w);
  }
  {
    float4* pp = (float4*)&pw[wave][0];
    pp[lane] = p0; pp[lane + 64] = p1; pp[lane + 128] = p2;
  }
  __syncthreads();

  // pass 3: reduce 8 partials, store bf16
  if (tid < 384) {
    float2 acc = make_float2(0.f, 0.f);
#pragma unroll
    for (int w = 0; w < 8; ++w) {
      float2 v = *(const float2*)&pw[w][tid * 2];
      acc.x += v.x; acc.y += v.y;
    }
    ushort2 o;
    o.x = f2bf(acc.x); o.y = f2bf(acc.y);
    *(ushort2*)(pooled_bf + (long long)blk * DD + tid * 2) = o;
  }
}

// ---------------------------------------------------------------------------
// K1: per (b, mt), 512 thr: stage A-tile (16 pooled rows) in LDS, then
// x = pooled@fc1^T + b (13 tiles, x -> LDS+global), qkv = x@ain^T + b
// (38 tiles) routed to q/k/vt scratch. Blocks 0-15 also zero `out`
// (deterministic, replay-safe zeroing for K2's atomicAdd accumulation).
// ---------------------------------------------------------------------------
__global__ __launch_bounds__(512, 4) void k_fc1qkv(
    const unsigned short* __restrict__ pooled,
    const unsigned short* __restrict__ fc1_wb, const float* __restrict__ fc1_b,
    const unsigned short* __restrict__ ain_wb, const float* __restrict__ ain_b,
    char* __restrict__ scratch, float* __restrict__ out)
{
  const int b = blockIdx.x / 3, mt = blockIdx.x % 3, m0 = mt * 16;
  const int tid = threadIdx.x, wv = tid >> 6, lane = tid & 63;
  const int col = lane & 15, quad = lane >> 4, koff = quad * 8;

  if (blockIdx.x < 16) out[blockIdx.x * 512 + tid] = 0.f;  // NB*32*2 = 8192 floats

  char* sb = scratch + (size_t)b * SB_BLK;
  float* x_f32 = (float*)(sb + SB_XF);
  unsigned short* q_bf  = (unsigned short*)(sb + SB_QB);
  unsigned short* k_bf  = (unsigned short*)(sb + SB_KB);
  unsigned short* vt_bf = (unsigned short*)(sb + SB_VT);

  __shared__ __align__(16) unsigned short sA[16][776];  // stride 776: row shift 4 banks
  __shared__ __align__(16) unsigned short xb[16][232];

  // stage A-tile: 16 rows x 768 bf16 (row src clamped to 32 for dead rows)
  {
    int r = tid >> 5, c = tid & 31;
    int src = m0 + r; if (src > 32) src = 32;
    const unsigned* gp = (const unsigned*)(pooled + (size_t)(b * SS + src) * DD);
    unsigned* lp = (unsigned*)&sA[r][0];
#pragma unroll
    for (int i = 0; i < 12; ++i) lp[c + 32 * i] = gp[c + 32 * i];
  }
  for (int u = tid; u < 16 * 16; u += 512) {
    int row = u >> 4, c = u & 15;
    ((unsigned*)&xb[row][200])[c] = 0u;
  }
  __syncthreads();

  for (int t = wv; t < 13; t += 8) {
    int n0 = t * 16;
    f4_t acc = mfma_tile_lds<24>(&sA[0][0] + col * 776 + koff,
                                 fc1_wb + (size_t)(n0 + col) * DD + koff);
    int gn = n0 + col;
    if (gn < DM) {
      float bv = fc1_b[gn];
#pragma unroll
      for (int r = 0; r < 4; ++r) {
        int row = quad * 4 + r;
        float v = acc[r] + bv;
        x_f32[(m0 + row) * 208 + gn] = v;
        xb[row][gn] = f2bf(v);
      }
    }
  }
  __syncthreads();

  for (int t = wv; t < 38; t += 8) {
    int n0 = t * 16;
    f4_t acc = mfma_tile_lds<7>(&xb[0][0] + col * 232 + koff,
                                ain_wb + (size_t)(n0 + col) * 224 + koff);
    int gn = n0 + col;
    if (gn < 600) {
      float bv = ain_b[gn];
#pragma unroll
      for (int r = 0; r < 4; ++r) {
        int gm = m0 + quad * 4 + r;
        unsigned short bfv = f2bf(acc[r] + bv);
        if (gn < 200)      q_bf[gm * 224 + gn] = bfv;
        else if (gn < 400) k_bf[gm * 224 + (gn - 200)] = bfv;
        else if (gm < SS)  vt_bf[(gn - 400) * 64 + gm] = bfv;   // V^T
      }
    }
  }
}

// ---------------------------------------------------------------------------
// K2: per (b, mt), 512 thr: 16 own Q-rows through attention + aout + LN1 +
// FFN + LN2, all intermediates in LDS; classifier partials folded in via
// atomicAdd to `out` (zeroed by K1).
// ---------------------------------------------------------------------------
__global__ __launch_bounds__(512, 4) void k_postattn(
    const unsigned short* __restrict__ aout_wb, const float* __restrict__ aout_b,
    const float* __restrict__ ln1_g, const float* __restrict__ ln1_b,
    const unsigned short* __restrict__ lin1_wb, const float* __restrict__ lin1_b,
    const unsigned short* __restrict__ lin2_wb, const float* __restrict__ lin2_b,
    const float* __restrict__ ln2_g, const float* __restrict__ ln2_b,
    const float* __restrict__ fcw, const float* __restrict__ fcb,
    char* __restrict__ scratch, float* __restrict__ out)
{
  const int b = blockIdx.x / 3, mt = blockIdx.x % 3, m0 = mt * 16;
  const int tid = threadIdx.x, wv = tid >> 6, lane = tid & 63;
  const int col = lane & 15, quad = lane >> 4, koff = quad * 8;

  char* sb = scratch + (size_t)b * SB_BLK;
  const unsigned short* q_bf  = (const unsigned short*)(sb + SB_QB);
  const unsigned short* k_bf  = (const unsigned short*)(sb + SB_KB);
  const unsigned short* vt_bf = (const unsigned short*)(sb + SB_VT);
  const float* x_f32 = (const float*)(sb + SB_XF);

  __shared__ float tc[16][211];                         // scores then C-tile
  __shared__ __align__(16) unsigned short Pb[16][72];   // softmax(P) bf16
  __shared__ __align__(16) unsigned short yb[16][232];  // LN1 out bf16
  __shared__ __align__(16) unsigned short fb[16][232];  // att, then f1
  for (int u = tid; u < 16 * 16; u += 512) {
    int row = u >> 4, c = u & 15;
    ((unsigned*)&yb[row][200])[c] = 0u;
    ((unsigned*)&fb[row][200])[c] = 0u;
  }

  // ---- S: scores rows m0..m0+15 vs all 48 K rows (3 tiles, K=224) ----
  for (int t = wv; t < 3; t += 8) {
    int n0 = t * 16;
    f4_t acc = mfma_tile<7>(q_bf + (m0 + col) * 224 + koff,
                            k_bf + (n0 + col) * 224 + koff);
    int gn = n0 + col;
#pragma unroll
    for (int r = 0; r < 4; ++r)
      tc[quad * 4 + r][gn] = acc[r] * 0.07071067811865475f;
  }
  __syncthreads();

  // ---- softmax rows (2 rows per wave), write P bf16 (pad-zeroed) ----
  for (int r = wv; r < 16; r += 8) {
    bool live = (m0 + r) < SS;
    float v = (lane < SS && live) ? tc[r][lane] : -__builtin_inff();
    float mx = v;
#pragma unroll
    for (int off = 32; off; off >>= 1) mx = fmaxf(mx, __shfl_xor(mx, off));
    float e = (lane < SS && live) ? __expf(v - mx) : 0.f;
    float sm = e;
#pragma unroll
    for (int off = 32; off; off >>= 1) sm += __shfl_xor(sm, off);
    Pb[r][lane] = (lane < SS && live) ? f2bf(e / sm) : (unsigned short)0;
  }
  __syncthreads();

  // ---- PV: att = P @ V  (13 tiles, K=64) -> fb bf16 ----
  for (int t = wv; t < 13; t += 8) {
    int n0 = t * 16;
    f4_t acc = mfma_tile_lds<2>(&Pb[0][0] + col * 72 + koff,
                                vt_bf + (n0 + col) * 64 + koff);
    int gn = n0 + col;
    if (gn < DM) {
#pragma unroll
      for (int r = 0; r < 4; ++r)
        fb[quad * 4 + r][gn] = f2bf(acc[r]);
    }
  }
  __syncthreads();

  // ---- A: y = x + att @ aout^T + b -> tc ----
  for (int t = wv; t < 13; t += 8) {
    int n0 = t * 16;
    f4_t acc = mfma_tile_lds<7>(&fb[0][0] + col * 232 + koff,
                                aout_wb + (size_t)(n0 + col) * 224 + koff);
    int gn = n0 + col;
    float bv = (gn < DM) ? aout_b[gn] : 0.f;
#pragma unroll
    for (int r = 0; r < 4; ++r) {
      int row = quad * 4 + r;
      float v = acc[r] + bv;
      if (gn < DM) v += x_f32[(m0 + row) * 208 + gn];
      tc[row][gn] = v;
    }
  }
  __syncthreads();

  // ---- LN1 -> tc (in place) + yb bf16 ----
  for (int r = wv; r < 16; r += 8) {
    float* p = &tc[r][0];
    float vals[4]; float s = 0.f;
#pragma unroll
    for (int i = 0; i < 4; ++i) { int k = lane + 64 * i; vals[i] = (k < DM) ? p[k] : 0.f; s += vals[i]; }
#pragma unroll
    for (int off = 32; off; off >>= 1) s += __shfl_xor(s, off);
    float mean = s * (1.f / DM);
    float vs = 0.f;
#pragma unroll
    for (int i = 0; i < 4; ++i) { int k = lane + 64 * i; if (k < DM) { float d = vals[i] - mean; vs += d * d; } }
#pragma unroll
    for (int off = 32; off; off >>= 1) vs += __shfl_xor(vs, off);
    float rstd = rsqrtf(vs * (1.f / DM) + 1e-5f);
#pragma unroll
    for (int i = 0; i < 4; ++i) {
      int k = lane + 64 * i;
      if (k < DM) {
        float o = (vals[i] - mean) * rstd * ln1_g[k] + ln1_b[k];
        p[k] = o;
        yb[r][k] = f2bf(o);
      }
    }
  }
  __syncthreads();

  // ---- C: f1 = relu(y @ lin1^T + b) -> fb (att dead) ----
  for (int t = wv; t < 13; t += 8) {
    int n0 = t * 16;
    f4_t acc = mfma_tile_lds<7>(&yb[0][0] + col * 232 + koff,
                                lin1_wb + (size_t)(n0 + col) * 224 + koff);
    int gn = n0 + col;
    if (gn < DM) {
      float bv = lin1_b[gn];
#pragma unroll
      for (int r = 0; r < 4; ++r)
        fb[quad * 4 + r][gn] = f2bf(fmaxf(acc[r] + bv, 0.f));
    }
  }
  __syncthreads();

  // ---- D: y2 = y + f1 @ lin2^T + b -> tc ----
  for (int t = wv; t < 13; t += 8) {
    int n0 = t * 16;
    f4_t acc = mfma_tile_lds<7>(&fb[0][0] + col * 232 + koff,
                                lin2_wb + (size_t)(n0 + col) * 224 + koff);
    int gn = n0 + col;
    if (gn < DM) {
      float bv = lin2_b[gn];
#pragma unroll
      for (int r = 0; r < 4; ++r) {
        int row = quad * 4 + r;
        tc[row][gn] = acc[r] + bv + tc[row][gn];
      }
    }
  }
  __syncthreads();

  // ---- LN2 -> tc in place ----
  for (int r = wv; r < 16; r += 8) {
    float* p = &tc[r][0];
    float vals[4]; float s = 0.f;
#pragma unroll
    for (int i = 0; i < 4; ++i) { int k = lane + 64 * i; vals[i] = (k < DM) ? p[k] : 0.f; s += vals[i]; }
#pragma unroll
    for (int off = 32; off; off >>= 1) s += __shfl_xor(s, off);
    float mean = s * (1.f / DM);
    float vs = 0.f;
#pragma unroll
    for (int i = 0; i < 4; ++i) { int k = lane + 64 * i; if (k < DM) { float d = vals[i] - mean; vs += d * d; } }
#pragma unroll
    for (int off = 32; off; off >>= 1) vs += __shfl_xor(vs, off);
    float rstd = rsqrtf(vs * (1.f / DM) + 1e-5f);
#pragma unroll
    for (int i = 0; i < 4; ++i) {
      int k = lane + 64 * i;
      if (k < DM) p[k] = (vals[i] - mean) * rstd * ln2_g[k] + ln2_b[k];
    }
  }
  __syncthreads();

  // ---- classifier partials (out zeroed by K1; atomicAdd combine) ----
  for (int r = wv; r < 16; r += 8) {
    int grow = m0 + r;
    if (grow >= SS) continue;
    const float* p = &tc[r][0];
    if (grow == 0) {
      // first-token broadcast term + bias, added to all 32 outputs of batch b
      float s0 = 0.f, s1 = 0.f;
#pragma unroll
      for (int i = 0; i < 4; ++i) {
        int k = lane + 64 * i;
        if (k < DM) { float v = p[k]; s0 += v * fcw[k]; s1 += v * fcw[400 + k]; }
      }
#pragma unroll
      for (int off = 32; off; off >>= 1) {
        s0 += __shfl_xor(s0, off);
        s1 += __shfl_xor(s1, off);
      }
      if (lane < 32) {
        atomicAdd(&out[(b * 32 + lane) * 2 + 0], s0 + fcb[0]);
        atomicAdd(&out[(b * 32 + lane) * 2 + 1], s1 + fcb[1]);
      }
    } else {
      int j = grow - 1;
      float a0 = 0.f, a1 = 0.f;
#pragma unroll
      for (int i = 0; i < 4; ++i) {
        int k = lane + 64 * i;
        if (k < DM) { float v = p[k]; a0 += v * fcw[200 + k]; a1 += v * fcw[600 + k]; }
      }
#pragma unroll
      for (int off = 32; off; off >>= 1) {
        a0 += __shfl_xor(a0, off);
        a1 += __shfl_xor(a1, off);
      }
      if (lane == 0) {
        atomicAdd(&out[(b * 32 + j) * 2 + 0], a0);
        atomicAdd(&out[(b * 32 + j) * 2 + 1], a1);
      }
    }
  }
}

// ---------------------------------------------------------------------------
extern "C" void kernel_launch(void* const* d_in, const int* in_sizes, int n_in,
                              void* d_out, int out_size, void* d_ws, size_t ws_size,
                              hipStream_t stream)
{
  (void)in_sizes; (void)n_in; (void)out_size; (void)ws_size;
  const float* hidden = (const float*)d_in[0];
  const int*   clause = (const int*)d_in[1];
  const float* fc5_w  = (const float*)d_in[2];
  const float* fc1_w  = (const float*)d_in[4];
  const float* fc1_b  = (const float*)d_in[5];
  const float* ain_w  = (const float*)d_in[6];
  const float* ain_b  = (const float*)d_in[7];
  const float* aout_w = (const float*)d_in[8];
  const float* aout_b = (const float*)d_in[9];
  const float* ln1_g  = (const float*)d_in[10];
  const float* ln1_b  = (const float*)d_in[11];
  const float* lin1_w = (const float*)d_in[12];
  const float* lin1_b = (const float*)d_in[13];
  const float* lin2_w = (const float*)d_in[14];
  const float* lin2_b = (const float*)d_in[15];
  const float* ln2_g  = (const float*)d_in[16];
  const float* ln2_b  = (const float*)d_in[17];
  const float* fc_w   = (const float*)d_in[18];
  const float* fc_b   = (const float*)d_in[19];
  float* out = (float*)d_out;

  char* w8 = (char*)d_ws;
  unsigned short* pooled_bf = (unsigned short*)(w8 + 0);  // [4224][768] + 32KB guard
  char* scratch = w8 + 6520832;                           // 128 * SB_BLK
  size_t wbase = 6520832 + (size_t)NB * SB_BLK;
  unsigned short* fc1_wb  = (unsigned short*)(w8 + wbase);
  unsigned short* ain_wb  = (unsigned short*)(w8 + wbase + 319488);
  unsigned short* aout_wb = (unsigned short*)(w8 + wbase + 591872);
  unsigned short* lin1_wb = (unsigned short*)(w8 + wbase + 685056);
  unsigned short* lin2_wb = (unsigned short*)(w8 + wbase + 778240);

  // 4224 pool blocks + 1187 convert/pad blocks
  pc_kernel<<<dim3(NB * SS + 1187), 512, 0, stream>>>(
      hidden, clause, fc5_w, pooled_bf,
      fc1_w, ain_w, aout_w, lin1_w, lin2_w,
      fc1_wb, ain_wb, aout_wb, lin1_wb, lin2_wb, scratch);
  k_fc1qkv<<<dim3(NB * 3), 512, 0, stream>>>(pooled_bf, fc1_wb, fc1_b,
      ain_wb, ain_b, scratch, out);
  k_postattn<<<dim3(NB * 3), 512, 0, stream>>>(aout_wb, aout_b, ln1_g, ln1_b,
      lin1_wb, lin1_b, lin2_wb, lin2_b, ln2_g, ln2_b, fc_w, fc_b,
      scratch, out);
}